// Round 9
// baseline (380.990 us; speedup 1.0000x reference)
//
#include <hip/hip_runtime.h>
#include <hip/hip_bf16.h>
#include <cstdint>

#define IN_DIM 128
#define OUT_STD 96
#define OUT_REP 32
#define OUT_ALL 128
#define NEG_SLOPE 0.2f
#define EE_BLOCKS 512
#define LOG2E 1.4426950408889634f

typedef _Float16 h2 __attribute__((ext_vector_type(2)));

// 32-lane group sum: 4 DPP stages (VALU) + one xor-16 ds_swizzle.
template <int CTRL>
__device__ __forceinline__ float dpp_add(float v)
{
    int x = __builtin_amdgcn_update_dpp(0, __float_as_int(v), CTRL, 0xf, 0xf, true);
    return v + __int_as_float(x);
}
__device__ __forceinline__ float grp32_sum(float v)
{
    v = dpp_add<0xB1>(v);   // quad_perm xor1
    v = dpp_add<0x4E>(v);   // quad_perm xor2
    v = dpp_add<0x141>(v);  // row_half_mirror (xor4)
    v = dpp_add<0x140>(v);  // row_mirror (xor8)
    int x = __builtin_amdgcn_ds_swizzle(__float_as_int(v), 0x401F); // xor16 within 32
    return v + __int_as_float(x);
}

// ---------------------------------------------------------------------------
// Mask dtype detection (JAX bool may arrive as uint8 / int32 / f32).
// ---------------------------------------------------------------------------
__global__ void mask_detect(const unsigned char* __restrict__ m, int* __restrict__ flag, int nbytes)
{
    int t = threadIdx.x;
    int anyGT1 = 0, any123 = 0;
    for (int i = t; i < nbytes; i += 64) {
        unsigned char b = m[i];
        if (b > 1) anyGT1 = 1;
        if ((i & 3) && b) any123 = 1;
    }
    anyGT1 = __any(anyGT1);
    any123 = __any(any123);
    if (t == 0) *flag = anyGT1 ? 2 : (any123 ? 0 : 1);
}

__device__ __forceinline__ bool mask_at(const void* m, int fl, int e)
{
    if (fl == 1) return ((const int*)m)[e] != 0;
    if (fl == 2) return ((const float*)m)[e] != 0.f;
    return ((const unsigned char*)m)[e] != 0;
}

// ---------------------------------------------------------------------------
// Edge encoder MLP 7->32->16 (+ deg histogram, + sums). ea written as f16.
// sums: [0..15] sum(ea), [16..31] sum(ea*mask), [32] sum(mask)
// ---------------------------------------------------------------------------
__global__ __launch_bounds__(256) void edge_enc(
    const float* __restrict__ raw, const int* __restrict__ ei,
    const void* __restrict__ mraw, const int* __restrict__ mflag,
    const float* __restrict__ w1, const float* __restrict__ b1,
    const float* __restrict__ w2, const float* __restrict__ b2,
    _Float16* __restrict__ ea, int* __restrict__ deg, float* __restrict__ sums, int E)
{
    __shared__ float sW1[7 * 32];
    __shared__ float sB1[32];
    __shared__ float sW2[32 * 16];
    __shared__ float sB2[16];
    __shared__ float red[33][4];
    int t = threadIdx.x;
    if (t < 224) sW1[t] = w1[t];
    if (t < 32)  sB1[t] = b1[t];
    for (int i = t; i < 512; i += 256) sW2[i] = w2[i];
    if (t < 16)  sB2[t] = b2[t];
    __syncthreads();
    int fl = *mflag;

    float accs[16], accm[16], cnt = 0.f;
#pragma unroll
    for (int j = 0; j < 16; ++j) { accs[j] = 0.f; accm[j] = 0.f; }

    for (int e = blockIdx.x * 256 + t; e < E; e += gridDim.x * 256) {
        float r[7];
#pragma unroll
        for (int k = 0; k < 7; ++k) r[k] = raw[(size_t)e * 7 + k];
        float o[16];
#pragma unroll
        for (int j = 0; j < 16; ++j) o[j] = sB2[j];
#pragma unroll
        for (int jh = 0; jh < 32; ++jh) {
            float hv = sB1[jh];
#pragma unroll
            for (int k = 0; k < 7; ++k) hv += r[k] * sW1[k * 32 + jh];
            hv = hv > 0.f ? hv : 0.f;
#pragma unroll
            for (int j = 0; j < 16; ++j) o[j] += hv * sW2[jh * 16 + j];
        }
        union { h2 h[8]; uint4 u[2]; } pk;
#pragma unroll
        for (int j = 0; j < 8; ++j) pk.h[j] = h2{(_Float16)o[2 * j], (_Float16)o[2 * j + 1]};
        uint4* dst = (uint4*)(ea + (size_t)e * 16);
        dst[0] = pk.u[0];
        dst[1] = pk.u[1];
        atomicAdd(&deg[ei[E + e]], 1);
        float mk = mask_at(mraw, fl, e) ? 1.f : 0.f;
#pragma unroll
        for (int j = 0; j < 16; ++j) { accs[j] += o[j]; accm[j] += o[j] * mk; }
        cnt += mk;
    }

    int wv = t >> 6, ln = t & 63;
#pragma unroll
    for (int j = 0; j < 16; ++j) {
        float v = accs[j], vm = accm[j];
#pragma unroll
        for (int off = 32; off; off >>= 1) {
            v  += __shfl_xor(v, off, 64);
            vm += __shfl_xor(vm, off, 64);
        }
        if (ln == 0) { red[j][wv] = v; red[16 + j][wv] = vm; }
    }
    {
        float c = cnt;
#pragma unroll
        for (int off = 32; off; off >>= 1) c += __shfl_xor(c, off, 64);
        if (ln == 0) red[32][wv] = c;
    }
    __syncthreads();
    if (t < 33) {
        float v = red[t][0] + red[t][1] + red[t][2] + red[t][3];
        atomicAdd(&sums[t], v);
    }
}

// ---------------------------------------------------------------------------
// CSR build
// ---------------------------------------------------------------------------
__global__ __launch_bounds__(256) void scan1(const int* __restrict__ deg, int* __restrict__ part, int n)
{
    __shared__ int sm[256];
    int i = blockIdx.x * 256 + threadIdx.x;
    sm[threadIdx.x] = (i < n) ? deg[i] : 0;
    __syncthreads();
    for (int s = 128; s; s >>= 1) {
        if (threadIdx.x < s) sm[threadIdx.x] += sm[threadIdx.x + s];
        __syncthreads();
    }
    if (threadIdx.x == 0) part[blockIdx.x] = sm[0];
}

__global__ __launch_bounds__(256) void scan2(int* __restrict__ part, int nb)
{
    __shared__ int sm[256];
    int t = threadIdx.x;
    int v = (t < nb) ? part[t] : 0;
    sm[t] = v;
    __syncthreads();
    for (int o = 1; o < 256; o <<= 1) {
        int add = (t >= o) ? sm[t - o] : 0;
        __syncthreads();
        sm[t] += add;
        __syncthreads();
    }
    if (t < nb) part[t] = sm[t] - v;  // exclusive
}

__global__ __launch_bounds__(256) void scan3(const int* __restrict__ deg, const int* __restrict__ part,
                                             int* __restrict__ row_ofs, int* __restrict__ cursor,
                                             int n, int E)
{
    __shared__ int sm[256];
    int t = threadIdx.x;
    int i = blockIdx.x * 256 + t;
    int v = (i < n) ? deg[i] : 0;
    sm[t] = v;
    __syncthreads();
    for (int o = 1; o < 256; o <<= 1) {
        int add = (t >= o) ? sm[t - o] : 0;
        __syncthreads();
        sm[t] += add;
        __syncthreads();
    }
    int excl = sm[t] - v + part[blockIdx.x];
    if (i < n) { row_ofs[i] = excl; cursor[i] = excl; }
    if (blockIdx.x == 0 && t == 0) row_ofs[n] = E;
}

// csr entry: {e | maskbit<<31, src}
__global__ __launch_bounds__(256) void csr_fill(const int* __restrict__ ei, int* __restrict__ cursor,
                                                const void* __restrict__ mraw, const int* __restrict__ mflag,
                                                uint2* __restrict__ csr, int E)
{
    int e = blockIdx.x * 256 + threadIdx.x;
    if (e < E) {
        int fl = *mflag;
        int s = ei[e];
        int d = ei[E + e];
        int slot = atomicAdd(&cursor[d], 1);
        unsigned int v = (unsigned int)e;
        if (mask_at(mraw, fl, e)) v |= 0x80000000u;
        csr[slot] = make_uint2(v, (unsigned int)s);
    }
}

// ---------------------------------------------------------------------------
// Node transforms (pack fused): XL[N][128] f16 (gathered side), XR[N][128] f32.
// Virtual B cols: [0,96)=wl_s | [96,128)=wl_r | [128,224)=wr_s | [224,256)=wr_r
// ---------------------------------------------------------------------------
#define GM_BM 64
#define GM_BK 16
__global__ __launch_bounds__(256) void node_gemm(
    const float* __restrict__ x,
    const float* __restrict__ wls, const float* __restrict__ wrs,
    const float* __restrict__ wlr, const float* __restrict__ wrr,
    const float* __restrict__ bls, const float* __restrict__ brs,
    const float* __restrict__ blr, const float* __restrict__ brr,
    _Float16* __restrict__ XLh, float* __restrict__ XR, int n)
{
    __shared__ __align__(16) float As[GM_BK][GM_BM];
    __shared__ __align__(16) float Bs[GM_BK][256];
    int tid = threadIdx.x;
    int tm = tid >> 5;   // 0..7
    int tn = tid & 31;   // 0..31
    int m0 = blockIdx.x * GM_BM;
    float acc[8][8] = {{0.f}};

    int rb = tid >> 4, cb0 = (tid & 15) * 16;
    const float* bsp; int bld, bc0;
    if (cb0 < 96)       { bsp = wls; bld = 96; bc0 = cb0; }
    else if (cb0 < 128) { bsp = wlr; bld = 32; bc0 = cb0 - 96; }
    else if (cb0 < 224) { bsp = wrs; bld = 96; bc0 = cb0 - 128; }
    else                { bsp = wrr; bld = 32; bc0 = cb0 - 224; }

    for (int k0 = 0; k0 < IN_DIM; k0 += GM_BK) {
        {
            int r = tid >> 2, c0 = (tid & 3) * 4;
            float4 av = make_float4(0.f, 0.f, 0.f, 0.f);
            if (m0 + r < n) av = *(const float4*)(x + (size_t)(m0 + r) * IN_DIM + k0 + c0);
            As[c0 + 0][r] = av.x; As[c0 + 1][r] = av.y;
            As[c0 + 2][r] = av.z; As[c0 + 3][r] = av.w;
        }
        {
            const float4* src = (const float4*)(bsp + (size_t)(k0 + rb) * bld + bc0);
            float4 b0 = src[0], b1 = src[1], b2 = src[2], b3 = src[3];
            *(float4*)&Bs[rb][cb0 + 0]  = b0; *(float4*)&Bs[rb][cb0 + 4]  = b1;
            *(float4*)&Bs[rb][cb0 + 8]  = b2; *(float4*)&Bs[rb][cb0 + 12] = b3;
        }
        __syncthreads();
#pragma unroll
        for (int k = 0; k < GM_BK; ++k) {
            float a[8], b[8];
            *(float4*)&a[0] = *(const float4*)&As[k][tm * 8];
            *(float4*)&a[4] = *(const float4*)&As[k][tm * 8 + 4];
#pragma unroll
            for (int j = 0; j < 8; ++j) b[j] = Bs[k][tn + 32 * j];
#pragma unroll
            for (int i = 0; i < 8; ++i)
#pragma unroll
                for (int j = 0; j < 8; ++j) acc[i][j] += a[i] * b[j];
        }
        __syncthreads();
    }

#pragma unroll
    for (int i = 0; i < 8; ++i) {
        int row = m0 + tm * 8 + i;
        if (row < n) {
#pragma unroll
            for (int j = 0; j < 4; ++j) {
                int col = tn + 32 * j;
                float b = col < 96 ? bls[col] : blr[col - 96];
                XLh[(size_t)row * 128 + col] = (_Float16)(acc[i][j] + b);
            }
#pragma unroll
            for (int j = 4; j < 8; ++j) {
                int c = tn + 32 * (j - 4);
                float b = c < 96 ? brs[c] : brr[c - 96];
                XR[(size_t)row * 128 + c] = acc[i][j] + b;
            }
        }
    }
}

// ---------------------------------------------------------------------------
// One edge: gather xls, ea-dot via v_fma_mix (f16 x f32 + f32), leaky,
// group-reduce -> score. Named scalars only.
// ---------------------------------------------------------------------------
__device__ __forceinline__ void edge_sc(
    const _Float16* __restrict__ XLh, const _Float16* __restrict__ ea,
    const uint2* __restrict__ csr, int pp, int f, bool is_std,
    float xr_n, float attv, const float* wef, float& s, float& x)
{
    uint2 pk = csr[pp];
    int e = __builtin_amdgcn_readfirstlane((int)(pk.x & 0x7fffffffu));
    bool act = is_std || (pk.x & 0x80000000u);
    int src = __builtin_amdgcn_readfirstlane((int)pk.y);
    x = (float)XLh[(size_t)src * 128 + f];
    union { uint4 u[2]; _Float16 h[16]; } pe;
    const uint4* eap = (const uint4*)(ea + (size_t)e * 16);
    pe.u[0] = eap[0]; pe.u[1] = eap[1];
    float efv = x + xr_n;
#pragma unroll
    for (int k = 0; k < 16; ++k)
        efv = fmaf((float)pe.h[k], wef[k], efv);   // v_fma_mix_f32
    float lk = fmaxf(efv, NEG_SLOPE * efv);
    float sv = grp32_sum(lk * attv);
    s = act ? sv : -INFINITY;
}

// ---------------------------------------------------------------------------
// Fused GATv2: one 128-thread block per node, lane = output feature.
// 8-wide straight-line batches (named scalars) + scalar remainder.
// ---------------------------------------------------------------------------
__global__ __launch_bounds__(128) void gat_main(
    const _Float16* __restrict__ XLh, const float* __restrict__ XR,
    const _Float16* __restrict__ ea, const uint2* __restrict__ csr,
    const int* __restrict__ row_ofs,
    const float* __restrict__ sums,
    const float* __restrict__ we_s, const float* __restrict__ we_r,
    const float* __restrict__ att_s, const float* __restrict__ att_r,
    const float* __restrict__ bias_s, const float* __restrict__ bias_r,
    float* __restrict__ out, int n, int E)
{
    int node = blockIdx.x;
    int f = threadIdx.x;
    bool is_std = f < OUT_STD;

    float wef[16];
    float efl = 0.f;
    {
        float c = sums[32]; c = c < 1.f ? 1.f : c;
        float scl = is_std ? (1.f / (float)E) : (1.f / c);
        const float* sp = is_std ? sums : (sums + 16);
#pragma unroll
        for (int k = 0; k < 16; ++k) {
            wef[k] = is_std ? we_s[k * OUT_STD + f] : we_r[k * OUT_REP + (f - OUT_STD)];
            efl += sp[k] * scl * wef[k];
        }
    }

    float attv  = (is_std ? att_s[f] : att_r[f - OUT_STD]) * LOG2E;
    float biasv = is_std ? bias_s[f] : bias_r[f - OUT_STD];

    float xl_n = (float)XLh[(size_t)node * 128 + f];
    float xr_n = XR[(size_t)node * 128 + f];

    float msg = xl_n + xr_n + efl;
    float lk0 = fmaxf(msg, NEG_SLOPE * msg);
    float m = grp32_sum(lk0 * attv);
    float denom = 1.f, acc = xl_n;

    int p0 = row_ofs[node], p1 = row_ofs[node + 1];
    int p = p0;
    for (; p + 8 <= p1; p += 8) {
        float s0, s1, s2, s3, s4, s5, s6, s7;
        float x0, x1, x2, x3, x4, x5, x6, x7;
        edge_sc(XLh, ea, csr, p + 0, f, is_std, xr_n, attv, wef, s0, x0);
        edge_sc(XLh, ea, csr, p + 1, f, is_std, xr_n, attv, wef, s1, x1);
        edge_sc(XLh, ea, csr, p + 2, f, is_std, xr_n, attv, wef, s2, x2);
        edge_sc(XLh, ea, csr, p + 3, f, is_std, xr_n, attv, wef, s3, x3);
        edge_sc(XLh, ea, csr, p + 4, f, is_std, xr_n, attv, wef, s4, x4);
        edge_sc(XLh, ea, csr, p + 5, f, is_std, xr_n, attv, wef, s5, x5);
        edge_sc(XLh, ea, csr, p + 6, f, is_std, xr_n, attv, wef, s6, x6);
        edge_sc(XLh, ea, csr, p + 7, f, is_std, xr_n, attv, wef, s7, x7);

        float mn = fmaxf(m, fmaxf(fmaxf(fmaxf(s0, s1), fmaxf(s2, s3)),
                                  fmaxf(fmaxf(s4, s5), fmaxf(s6, s7))));
        float r  = exp2f(m - mn);
        float q0 = exp2f(s0 - mn), q1 = exp2f(s1 - mn);
        float q2 = exp2f(s2 - mn), q3 = exp2f(s3 - mn);
        float q4 = exp2f(s4 - mn), q5 = exp2f(s5 - mn);
        float q6 = exp2f(s6 - mn), q7 = exp2f(s7 - mn);
        denom = denom * r + (((q0 + q1) + (q2 + q3)) + ((q4 + q5) + (q6 + q7)));
        acc   = acc * r + (((q0 * x0 + q1 * x1) + (q2 * x2 + q3 * x3))
                         + ((q4 * x4 + q5 * x5) + (q6 * x6 + q7 * x7)));
        m = mn;
    }
    for (; p < p1; ++p) {
        float s8, x8;
        edge_sc(XLh, ea, csr, p, f, is_std, xr_n, attv, wef, s8, x8);
        float mn = fmaxf(m, s8);
        float r  = exp2f(m - mn);
        float q  = exp2f(s8 - mn);
        denom = denom * r + q;
        acc   = acc * r + q * x8;
        m = mn;
    }
    out[(size_t)node * OUT_ALL + f] = acc / denom + biasv;
}

// ---------------------------------------------------------------------------
extern "C" void kernel_launch(void* const* d_in, const int* in_sizes, int n_in,
                              void* d_out, int out_size, void* d_ws, size_t ws_size,
                              hipStream_t stream)
{
    const float* x    = (const float*)d_in[0];
    const float* raw  = (const float*)d_in[1];
    const int*   ei   = (const int*)d_in[2];
    const void*  mask_raw = d_in[3];
    const float* ee_w1 = (const float*)d_in[4];
    const float* ee_b1 = (const float*)d_in[5];
    const float* ee_w2 = (const float*)d_in[6];
    const float* ee_b2 = (const float*)d_in[7];
    const float* wl_s = (const float*)d_in[8];
    const float* bl_s = (const float*)d_in[9];
    const float* wr_s = (const float*)d_in[10];
    const float* br_s = (const float*)d_in[11];
    const float* we_s = (const float*)d_in[12];
    const float* att_s = (const float*)d_in[13];
    const float* bias_s = (const float*)d_in[14];
    const float* wl_r = (const float*)d_in[15];
    const float* bl_r = (const float*)d_in[16];
    const float* wr_r = (const float*)d_in[17];
    const float* br_r = (const float*)d_in[18];
    const float* we_r = (const float*)d_in[19];
    const float* att_r = (const float*)d_in[20];
    const float* bias_r = (const float*)d_in[21];

    const int N = in_sizes[0] / IN_DIM;
    const int E = in_sizes[1] / 7;

    char* w = (char*)d_ws;
    size_t off = 0;
    auto carve = [&](size_t bytes) {
        void* p = w + off;
        off = (off + bytes + 255) & ~(size_t)255;
        return p;
    };
    _Float16* XLh  = (_Float16*)carve((size_t)N * 128 * 2);
    float* XR      = (float*)carve((size_t)N * 128 * 4);
    _Float16* ea   = (_Float16*)carve((size_t)E * 16 * 2);
    uint2* csr     = (uint2*)carve((size_t)E * 8);
    int*   row_ofs = (int*)carve((size_t)(N + 1) * 4);
    int*   cursor  = (int*)carve((size_t)N * 4);
    int*   deg     = (int*)carve((size_t)N * 4);
    int*   part    = (int*)carve(1024);
    float* sums    = (float*)carve(256);
    int*   mflag   = (int*)carve(256);
    (void)ws_size; (void)n_in; (void)out_size;

    hipMemsetAsync(deg, 0, (size_t)N * 4, stream);
    hipMemsetAsync(sums, 0, 256, stream);

    int ebl = (E + 255) / 256;
    int nbl = (N + 255) / 256;

    int nprobe = E < 4096 ? E : 4096;
    mask_detect<<<1, 64, 0, stream>>>((const unsigned char*)mask_raw, mflag, nprobe);

    int eebl = ebl < EE_BLOCKS ? ebl : EE_BLOCKS;
    edge_enc<<<eebl, 256, 0, stream>>>(raw, ei, mask_raw, mflag, ee_w1, ee_b1, ee_w2, ee_b2, ea, deg, sums, E);
    scan1<<<nbl, 256, 0, stream>>>(deg, part, N);
    scan2<<<1, 256, 0, stream>>>(part, nbl);
    scan3<<<nbl, 256, 0, stream>>>(deg, part, row_ofs, cursor, N, E);
    csr_fill<<<ebl, 256, 0, stream>>>(ei, cursor, mask_raw, mflag, csr, E);
    node_gemm<<<(N + GM_BM - 1) / GM_BM, 256, 0, stream>>>(
        x, wl_s, wr_s, wl_r, wr_r, bl_s, br_s, bl_r, br_r, XLh, XR, N);
    gat_main<<<N, 128, 0, stream>>>(XLh, XR, ea, csr, row_ofs, sums,
                                    we_s, we_r, att_s, att_r, bias_s, bias_r,
                                    (float*)d_out, N, E);
}

// Round 10
// 364.874 us; speedup vs baseline: 1.0442x; 1.0442x over previous
//
#include <hip/hip_runtime.h>
#include <hip/hip_bf16.h>
#include <cstdint>

#define IN_DIM 128
#define OUT_STD 96
#define OUT_REP 32
#define OUT_ALL 128
#define NEG_SLOPE 0.2f
#define EE_BLOCKS 512
#define LOG2E 1.4426950408889634f

typedef _Float16 h2 __attribute__((ext_vector_type(2)));

// 32-lane group sum: 4 DPP stages (VALU) + one xor-16 ds_swizzle.
template <int CTRL>
__device__ __forceinline__ float dpp_add(float v)
{
    int x = __builtin_amdgcn_update_dpp(0, __float_as_int(v), CTRL, 0xf, 0xf, true);
    return v + __int_as_float(x);
}
__device__ __forceinline__ float grp32_sum(float v)
{
    v = dpp_add<0xB1>(v);   // quad_perm xor1
    v = dpp_add<0x4E>(v);   // quad_perm xor2
    v = dpp_add<0x141>(v);  // row_half_mirror (xor4)
    v = dpp_add<0x140>(v);  // row_mirror (xor8)
    int x = __builtin_amdgcn_ds_swizzle(__float_as_int(v), 0x401F); // xor16 within 32
    return v + __int_as_float(x);
}

// ---------------------------------------------------------------------------
// Mask dtype detection (JAX bool may arrive as uint8 / int32 / f32).
// ---------------------------------------------------------------------------
__global__ void mask_detect(const unsigned char* __restrict__ m, int* __restrict__ flag, int nbytes)
{
    int t = threadIdx.x;
    int anyGT1 = 0, any123 = 0;
    for (int i = t; i < nbytes; i += 64) {
        unsigned char b = m[i];
        if (b > 1) anyGT1 = 1;
        if ((i & 3) && b) any123 = 1;
    }
    anyGT1 = __any(anyGT1);
    any123 = __any(any123);
    if (t == 0) *flag = anyGT1 ? 2 : (any123 ? 0 : 1);
}

__device__ __forceinline__ bool mask_at(const void* m, int fl, int e)
{
    if (fl == 1) return ((const int*)m)[e] != 0;
    if (fl == 2) return ((const float*)m)[e] != 0.f;
    return ((const unsigned char*)m)[e] != 0;
}

// ---------------------------------------------------------------------------
// Edge encoder MLP 7->32->16 (+ deg histogram, + sums). ea written as f16.
// sums: [0..15] sum(ea), [16..31] sum(ea*mask), [32] sum(mask)
// ---------------------------------------------------------------------------
__global__ __launch_bounds__(256) void edge_enc(
    const float* __restrict__ raw, const int* __restrict__ ei,
    const void* __restrict__ mraw, const int* __restrict__ mflag,
    const float* __restrict__ w1, const float* __restrict__ b1,
    const float* __restrict__ w2, const float* __restrict__ b2,
    _Float16* __restrict__ ea, int* __restrict__ deg, float* __restrict__ sums, int E)
{
    __shared__ float sW1[7 * 32];
    __shared__ float sB1[32];
    __shared__ float sW2[32 * 16];
    __shared__ float sB2[16];
    __shared__ float red[33][4];
    int t = threadIdx.x;
    if (t < 224) sW1[t] = w1[t];
    if (t < 32)  sB1[t] = b1[t];
    for (int i = t; i < 512; i += 256) sW2[i] = w2[i];
    if (t < 16)  sB2[t] = b2[t];
    __syncthreads();
    int fl = *mflag;

    float accs[16], accm[16], cnt = 0.f;
#pragma unroll
    for (int j = 0; j < 16; ++j) { accs[j] = 0.f; accm[j] = 0.f; }

    for (int e = blockIdx.x * 256 + t; e < E; e += gridDim.x * 256) {
        float r[7];
#pragma unroll
        for (int k = 0; k < 7; ++k) r[k] = raw[(size_t)e * 7 + k];
        float o[16];
#pragma unroll
        for (int j = 0; j < 16; ++j) o[j] = sB2[j];
#pragma unroll
        for (int jh = 0; jh < 32; ++jh) {
            float hv = sB1[jh];
#pragma unroll
            for (int k = 0; k < 7; ++k) hv += r[k] * sW1[k * 32 + jh];
            hv = hv > 0.f ? hv : 0.f;
#pragma unroll
            for (int j = 0; j < 16; ++j) o[j] += hv * sW2[jh * 16 + j];
        }
        union { h2 h[8]; uint4 u[2]; } pk;
#pragma unroll
        for (int j = 0; j < 8; ++j) pk.h[j] = h2{(_Float16)o[2 * j], (_Float16)o[2 * j + 1]};
        uint4* dst = (uint4*)(ea + (size_t)e * 16);
        dst[0] = pk.u[0];
        dst[1] = pk.u[1];
        atomicAdd(&deg[ei[E + e]], 1);
        float mk = mask_at(mraw, fl, e) ? 1.f : 0.f;
#pragma unroll
        for (int j = 0; j < 16; ++j) { accs[j] += o[j]; accm[j] += o[j] * mk; }
        cnt += mk;
    }

    int wv = t >> 6, ln = t & 63;
#pragma unroll
    for (int j = 0; j < 16; ++j) {
        float v = accs[j], vm = accm[j];
#pragma unroll
        for (int off = 32; off; off >>= 1) {
            v  += __shfl_xor(v, off, 64);
            vm += __shfl_xor(vm, off, 64);
        }
        if (ln == 0) { red[j][wv] = v; red[16 + j][wv] = vm; }
    }
    {
        float c = cnt;
#pragma unroll
        for (int off = 32; off; off >>= 1) c += __shfl_xor(c, off, 64);
        if (ln == 0) red[32][wv] = c;
    }
    __syncthreads();
    if (t < 33) {
        float v = red[t][0] + red[t][1] + red[t][2] + red[t][3];
        atomicAdd(&sums[t], v);
    }
}

// ---------------------------------------------------------------------------
// CSR build
// ---------------------------------------------------------------------------
__global__ __launch_bounds__(256) void scan1(const int* __restrict__ deg, int* __restrict__ part, int n)
{
    __shared__ int sm[256];
    int i = blockIdx.x * 256 + threadIdx.x;
    sm[threadIdx.x] = (i < n) ? deg[i] : 0;
    __syncthreads();
    for (int s = 128; s; s >>= 1) {
        if (threadIdx.x < s) sm[threadIdx.x] += sm[threadIdx.x + s];
        __syncthreads();
    }
    if (threadIdx.x == 0) part[blockIdx.x] = sm[0];
}

__global__ __launch_bounds__(256) void scan2(int* __restrict__ part, int nb)
{
    __shared__ int sm[256];
    int t = threadIdx.x;
    int v = (t < nb) ? part[t] : 0;
    sm[t] = v;
    __syncthreads();
    for (int o = 1; o < 256; o <<= 1) {
        int add = (t >= o) ? sm[t - o] : 0;
        __syncthreads();
        sm[t] += add;
        __syncthreads();
    }
    if (t < nb) part[t] = sm[t] - v;  // exclusive
}

__global__ __launch_bounds__(256) void scan3(const int* __restrict__ deg, const int* __restrict__ part,
                                             int* __restrict__ row_ofs, int* __restrict__ cursor,
                                             int n, int E)
{
    __shared__ int sm[256];
    int t = threadIdx.x;
    int i = blockIdx.x * 256 + t;
    int v = (i < n) ? deg[i] : 0;
    sm[t] = v;
    __syncthreads();
    for (int o = 1; o < 256; o <<= 1) {
        int add = (t >= o) ? sm[t - o] : 0;
        __syncthreads();
        sm[t] += add;
        __syncthreads();
    }
    int excl = sm[t] - v + part[blockIdx.x];
    if (i < n) { row_ofs[i] = excl; cursor[i] = excl; }
    if (blockIdx.x == 0 && t == 0) row_ofs[n] = E;
}

// csr entry: {e | maskbit<<31, src}
__global__ __launch_bounds__(256) void csr_fill(const int* __restrict__ ei, int* __restrict__ cursor,
                                                const void* __restrict__ mraw, const int* __restrict__ mflag,
                                                uint2* __restrict__ csr, int E)
{
    int e = blockIdx.x * 256 + threadIdx.x;
    if (e < E) {
        int fl = *mflag;
        int s = ei[e];
        int d = ei[E + e];
        int slot = atomicAdd(&cursor[d], 1);
        unsigned int v = (unsigned int)e;
        if (mask_at(mraw, fl, e)) v |= 0x80000000u;
        csr[slot] = make_uint2(v, (unsigned int)s);
    }
}

// ---------------------------------------------------------------------------
// Node transforms (pack fused): XL[N][128] f16 (gathered side), XR[N][128] f32.
// Virtual B cols: [0,96)=wl_s | [96,128)=wl_r | [128,224)=wr_s | [224,256)=wr_r
// ---------------------------------------------------------------------------
#define GM_BM 64
#define GM_BK 16
__global__ __launch_bounds__(256) void node_gemm(
    const float* __restrict__ x,
    const float* __restrict__ wls, const float* __restrict__ wrs,
    const float* __restrict__ wlr, const float* __restrict__ wrr,
    const float* __restrict__ bls, const float* __restrict__ brs,
    const float* __restrict__ blr, const float* __restrict__ brr,
    _Float16* __restrict__ XLh, float* __restrict__ XR, int n)
{
    __shared__ __align__(16) float As[GM_BK][GM_BM];
    __shared__ __align__(16) float Bs[GM_BK][256];
    int tid = threadIdx.x;
    int tm = tid >> 5;   // 0..7
    int tn = tid & 31;   // 0..31
    int m0 = blockIdx.x * GM_BM;
    float acc[8][8] = {{0.f}};

    int rb = tid >> 4, cb0 = (tid & 15) * 16;
    const float* bsp; int bld, bc0;
    if (cb0 < 96)       { bsp = wls; bld = 96; bc0 = cb0; }
    else if (cb0 < 128) { bsp = wlr; bld = 32; bc0 = cb0 - 96; }
    else if (cb0 < 224) { bsp = wrs; bld = 96; bc0 = cb0 - 128; }
    else                { bsp = wrr; bld = 32; bc0 = cb0 - 224; }

    for (int k0 = 0; k0 < IN_DIM; k0 += GM_BK) {
        {
            int r = tid >> 2, c0 = (tid & 3) * 4;
            float4 av = make_float4(0.f, 0.f, 0.f, 0.f);
            if (m0 + r < n) av = *(const float4*)(x + (size_t)(m0 + r) * IN_DIM + k0 + c0);
            As[c0 + 0][r] = av.x; As[c0 + 1][r] = av.y;
            As[c0 + 2][r] = av.z; As[c0 + 3][r] = av.w;
        }
        {
            const float4* src = (const float4*)(bsp + (size_t)(k0 + rb) * bld + bc0);
            float4 b0 = src[0], b1 = src[1], b2 = src[2], b3 = src[3];
            *(float4*)&Bs[rb][cb0 + 0]  = b0; *(float4*)&Bs[rb][cb0 + 4]  = b1;
            *(float4*)&Bs[rb][cb0 + 8]  = b2; *(float4*)&Bs[rb][cb0 + 12] = b3;
        }
        __syncthreads();
#pragma unroll
        for (int k = 0; k < GM_BK; ++k) {
            float a[8], b[8];
            *(float4*)&a[0] = *(const float4*)&As[k][tm * 8];
            *(float4*)&a[4] = *(const float4*)&As[k][tm * 8 + 4];
#pragma unroll
            for (int j = 0; j < 8; ++j) b[j] = Bs[k][tn + 32 * j];
#pragma unroll
            for (int i = 0; i < 8; ++i)
#pragma unroll
                for (int j = 0; j < 8; ++j) acc[i][j] += a[i] * b[j];
        }
        __syncthreads();
    }

#pragma unroll
    for (int i = 0; i < 8; ++i) {
        int row = m0 + tm * 8 + i;
        if (row < n) {
#pragma unroll
            for (int j = 0; j < 4; ++j) {
                int col = tn + 32 * j;
                float b = col < 96 ? bls[col] : blr[col - 96];
                XLh[(size_t)row * 128 + col] = (_Float16)(acc[i][j] + b);
            }
#pragma unroll
            for (int j = 4; j < 8; ++j) {
                int c = tn + 32 * (j - 4);
                float b = c < 96 ? brs[c] : brr[c - 96];
                XR[(size_t)row * 128 + c] = acc[i][j] + b;
            }
        }
    }
}

// ---------------------------------------------------------------------------
// One edge: gather xls, ea-dot via fdot2, leaky, group-reduce -> score.
// Weights passed BY VALUE as named scalars (no addressable local array).
// ---------------------------------------------------------------------------
__device__ __forceinline__ void edge_sc(
    const _Float16* __restrict__ XLh, const _Float16* __restrict__ ea,
    const uint2* __restrict__ csr, int pp, int f, bool is_std,
    float xr_n, float attv,
    h2 w0, h2 w1, h2 w2, h2 w3, h2 w4, h2 w5, h2 w6, h2 w7,
    float& s, float& x)
{
    uint2 pk = csr[pp];
    int e = __builtin_amdgcn_readfirstlane((int)(pk.x & 0x7fffffffu));
    bool act = is_std || (pk.x & 0x80000000u);
    int src = __builtin_amdgcn_readfirstlane((int)pk.y);
    x = (float)XLh[(size_t)src * 128 + f];
    union { uint4 u[2]; h2 h[8]; } pe;
    const uint4* eap = (const uint4*)(ea + (size_t)e * 16);
    pe.u[0] = eap[0]; pe.u[1] = eap[1];
    float efv = x + xr_n;
    efv = __builtin_amdgcn_fdot2(pe.h[0], w0, efv, false);
    efv = __builtin_amdgcn_fdot2(pe.h[1], w1, efv, false);
    efv = __builtin_amdgcn_fdot2(pe.h[2], w2, efv, false);
    efv = __builtin_amdgcn_fdot2(pe.h[3], w3, efv, false);
    efv = __builtin_amdgcn_fdot2(pe.h[4], w4, efv, false);
    efv = __builtin_amdgcn_fdot2(pe.h[5], w5, efv, false);
    efv = __builtin_amdgcn_fdot2(pe.h[6], w6, efv, false);
    efv = __builtin_amdgcn_fdot2(pe.h[7], w7, efv, false);
    float lk = fmaxf(efv, NEG_SLOPE * efv);
    float sv = grp32_sum(lk * attv);
    s = act ? sv : -INFINITY;
}

// ---------------------------------------------------------------------------
// Fused GATv2: one 128-thread block per node, lane = output feature.
// 8-wide straight-line batches, all-named-scalar state, fdot2 ea-dot.
// ---------------------------------------------------------------------------
__global__ __launch_bounds__(128, 4) void gat_main(
    const _Float16* __restrict__ XLh, const float* __restrict__ XR,
    const _Float16* __restrict__ ea, const uint2* __restrict__ csr,
    const int* __restrict__ row_ofs,
    const float* __restrict__ sums,
    const float* __restrict__ we_s, const float* __restrict__ we_r,
    const float* __restrict__ att_s, const float* __restrict__ att_r,
    const float* __restrict__ bias_s, const float* __restrict__ bias_r,
    float* __restrict__ out, int n, int E)
{
    int node = blockIdx.x;
    int f = threadIdx.x;
    bool is_std = f < OUT_STD;

    const float* wsrc = is_std ? we_s : we_r;
    int ldw = is_std ? OUT_STD : OUT_REP;
    int fc  = is_std ? f : (f - OUT_STD);
    const float* sp = is_std ? sums : (sums + 16);
    float c = sums[32]; c = c < 1.f ? 1.f : c;
    float scl = is_std ? (1.f / (float)E) : (1.f / c);

    float efl;
    h2 w0, w1, w2, w3, w4, w5, w6, w7;
    {
        float v0, v1;
#define LOADW(idx, dst, k0, k1)                                      \
        v0 = wsrc[(k0) * ldw + fc]; v1 = wsrc[(k1) * ldw + fc];      \
        dst = h2{(_Float16)v0, (_Float16)v1};                        \
        efl += sp[k0] * scl * v0 + sp[k1] * scl * v1;
        efl = 0.f;
        LOADW(0, w0, 0, 1)  LOADW(1, w1, 2, 3)
        LOADW(2, w2, 4, 5)  LOADW(3, w3, 6, 7)
        LOADW(4, w4, 8, 9)  LOADW(5, w5, 10, 11)
        LOADW(6, w6, 12, 13) LOADW(7, w7, 14, 15)
#undef LOADW
    }

    float attv  = (is_std ? att_s[f] : att_r[fc]) * LOG2E;
    float biasv = is_std ? bias_s[f] : bias_r[fc];

    float xl_n = (float)XLh[(size_t)node * 128 + f];
    float xr_n = XR[(size_t)node * 128 + f];

    float msg = xl_n + xr_n + efl;
    float lk0 = fmaxf(msg, NEG_SLOPE * msg);
    float m = grp32_sum(lk0 * attv);
    float denom = 1.f, acc = xl_n;

    int p0 = row_ofs[node], p1 = row_ofs[node + 1];
    int p = p0;
    for (; p + 8 <= p1; p += 8) {
        float s0, s1, s2, s3, s4, s5, s6, s7;
        float x0, x1, x2, x3, x4, x5, x6, x7;
        edge_sc(XLh, ea, csr, p + 0, f, is_std, xr_n, attv, w0, w1, w2, w3, w4, w5, w6, w7, s0, x0);
        edge_sc(XLh, ea, csr, p + 1, f, is_std, xr_n, attv, w0, w1, w2, w3, w4, w5, w6, w7, s1, x1);
        edge_sc(XLh, ea, csr, p + 2, f, is_std, xr_n, attv, w0, w1, w2, w3, w4, w5, w6, w7, s2, x2);
        edge_sc(XLh, ea, csr, p + 3, f, is_std, xr_n, attv, w0, w1, w2, w3, w4, w5, w6, w7, s3, x3);
        edge_sc(XLh, ea, csr, p + 4, f, is_std, xr_n, attv, w0, w1, w2, w3, w4, w5, w6, w7, s4, x4);
        edge_sc(XLh, ea, csr, p + 5, f, is_std, xr_n, attv, w0, w1, w2, w3, w4, w5, w6, w7, s5, x5);
        edge_sc(XLh, ea, csr, p + 6, f, is_std, xr_n, attv, w0, w1, w2, w3, w4, w5, w6, w7, s6, x6);
        edge_sc(XLh, ea, csr, p + 7, f, is_std, xr_n, attv, w0, w1, w2, w3, w4, w5, w6, w7, s7, x7);

        float mn = fmaxf(m, fmaxf(fmaxf(fmaxf(s0, s1), fmaxf(s2, s3)),
                                  fmaxf(fmaxf(s4, s5), fmaxf(s6, s7))));
        float r  = exp2f(m - mn);
        float q0 = exp2f(s0 - mn), q1 = exp2f(s1 - mn);
        float q2 = exp2f(s2 - mn), q3 = exp2f(s3 - mn);
        float q4 = exp2f(s4 - mn), q5 = exp2f(s5 - mn);
        float q6 = exp2f(s6 - mn), q7 = exp2f(s7 - mn);
        denom = denom * r + (((q0 + q1) + (q2 + q3)) + ((q4 + q5) + (q6 + q7)));
        acc   = acc * r + (((q0 * x0 + q1 * x1) + (q2 * x2 + q3 * x3))
                         + ((q4 * x4 + q5 * x5) + (q6 * x6 + q7 * x7)));
        m = mn;
    }
    for (; p < p1; ++p) {
        float s8, x8;
        edge_sc(XLh, ea, csr, p, f, is_std, xr_n, attv, w0, w1, w2, w3, w4, w5, w6, w7, s8, x8);
        float mn = fmaxf(m, s8);
        float r  = exp2f(m - mn);
        float q  = exp2f(s8 - mn);
        denom = denom * r + q;
        acc   = acc * r + q * x8;
        m = mn;
    }
    out[(size_t)node * OUT_ALL + f] = acc / denom + biasv;
}

// ---------------------------------------------------------------------------
extern "C" void kernel_launch(void* const* d_in, const int* in_sizes, int n_in,
                              void* d_out, int out_size, void* d_ws, size_t ws_size,
                              hipStream_t stream)
{
    const float* x    = (const float*)d_in[0];
    const float* raw  = (const float*)d_in[1];
    const int*   ei   = (const int*)d_in[2];
    const void*  mask_raw = d_in[3];
    const float* ee_w1 = (const float*)d_in[4];
    const float* ee_b1 = (const float*)d_in[5];
    const float* ee_w2 = (const float*)d_in[6];
    const float* ee_b2 = (const float*)d_in[7];
    const float* wl_s = (const float*)d_in[8];
    const float* bl_s = (const float*)d_in[9];
    const float* wr_s = (const float*)d_in[10];
    const float* br_s = (const float*)d_in[11];
    const float* we_s = (const float*)d_in[12];
    const float* att_s = (const float*)d_in[13];
    const float* bias_s = (const float*)d_in[14];
    const float* wl_r = (const float*)d_in[15];
    const float* bl_r = (const float*)d_in[16];
    const float* wr_r = (const float*)d_in[17];
    const float* br_r = (const float*)d_in[18];
    const float* we_r = (const float*)d_in[19];
    const float* att_r = (const float*)d_in[20];
    const float* bias_r = (const float*)d_in[21];

    const int N = in_sizes[0] / IN_DIM;
    const int E = in_sizes[1] / 7;

    char* w = (char*)d_ws;
    size_t off = 0;
    auto carve = [&](size_t bytes) {
        void* p = w + off;
        off = (off + bytes + 255) & ~(size_t)255;
        return p;
    };
    _Float16* XLh  = (_Float16*)carve((size_t)N * 128 * 2);
    float* XR      = (float*)carve((size_t)N * 128 * 4);
    _Float16* ea   = (_Float16*)carve((size_t)E * 16 * 2);
    uint2* csr     = (uint2*)carve((size_t)E * 8);
    int*   row_ofs = (int*)carve((size_t)(N + 1) * 4);
    int*   cursor  = (int*)carve((size_t)N * 4);
    int*   deg     = (int*)carve((size_t)N * 4);
    int*   part    = (int*)carve(1024);
    float* sums    = (float*)carve(256);
    int*   mflag   = (int*)carve(256);
    (void)ws_size; (void)n_in; (void)out_size;

    hipMemsetAsync(deg, 0, (size_t)N * 4, stream);
    hipMemsetAsync(sums, 0, 256, stream);

    int ebl = (E + 255) / 256;
    int nbl = (N + 255) / 256;

    int nprobe = E < 4096 ? E : 4096;
    mask_detect<<<1, 64, 0, stream>>>((const unsigned char*)mask_raw, mflag, nprobe);

    int eebl = ebl < EE_BLOCKS ? ebl : EE_BLOCKS;
    edge_enc<<<eebl, 256, 0, stream>>>(raw, ei, mask_raw, mflag, ee_w1, ee_b1, ee_w2, ee_b2, ea, deg, sums, E);
    scan1<<<nbl, 256, 0, stream>>>(deg, part, N);
    scan2<<<1, 256, 0, stream>>>(part, nbl);
    scan3<<<nbl, 256, 0, stream>>>(deg, part, row_ofs, cursor, N, E);
    csr_fill<<<ebl, 256, 0, stream>>>(ei, cursor, mask_raw, mflag, csr, E);
    node_gemm<<<(N + GM_BM - 1) / GM_BM, 256, 0, stream>>>(
        x, wl_s, wr_s, wl_r, wr_r, bl_s, br_s, bl_r, br_r, XLh, XR, N);
    gat_main<<<N, 128, 0, stream>>>(XLh, XR, ea, csr, row_ofs, sums,
                                    we_s, we_r, att_s, att_r, bias_s, bias_r,
                                    (float*)d_out, N, E);
}

// Round 12
// 313.328 us; speedup vs baseline: 1.2159x; 1.1645x over previous
//
#include <hip/hip_runtime.h>
#include <hip/hip_bf16.h>
#include <cstdint>

#define IN_DIM 128
#define OUT_STD 96
#define OUT_REP 32
#define OUT_ALL 128
#define NEG_SLOPE 0.2f
#define EE_BLOCKS 512
#define LOG2E 1.4426950408889634f

typedef _Float16 h2 __attribute__((ext_vector_type(2)));
typedef _Float16 f16x8 __attribute__((ext_vector_type(8)));
typedef float f32x4 __attribute__((ext_vector_type(4)));

// 32-lane group sum: 4 DPP stages (VALU) + one xor-16 ds_swizzle.
template <int CTRL>
__device__ __forceinline__ float dpp_add(float v)
{
    int x = __builtin_amdgcn_update_dpp(0, __float_as_int(v), CTRL, 0xf, 0xf, true);
    return v + __int_as_float(x);
}
__device__ __forceinline__ float grp32_sum(float v)
{
    v = dpp_add<0xB1>(v);   // quad_perm xor1
    v = dpp_add<0x4E>(v);   // quad_perm xor2
    v = dpp_add<0x141>(v);  // row_half_mirror (xor4)
    v = dpp_add<0x140>(v);  // row_mirror (xor8)
    int x = __builtin_amdgcn_ds_swizzle(__float_as_int(v), 0x401F); // xor16 within 32
    return v + __int_as_float(x);
}

// ---------------------------------------------------------------------------
__global__ void mask_detect(const unsigned char* __restrict__ m, int* __restrict__ flag, int nbytes)
{
    int t = threadIdx.x;
    int anyGT1 = 0, any123 = 0;
    for (int i = t; i < nbytes; i += 64) {
        unsigned char b = m[i];
        if (b > 1) anyGT1 = 1;
        if ((i & 3) && b) any123 = 1;
    }
    anyGT1 = __any(anyGT1);
    any123 = __any(any123);
    if (t == 0) *flag = anyGT1 ? 2 : (any123 ? 0 : 1);
}

__device__ __forceinline__ bool mask_at(const void* m, int fl, int e)
{
    if (fl == 1) return ((const int*)m)[e] != 0;
    if (fl == 2) return ((const float*)m)[e] != 0.f;
    return ((const unsigned char*)m)[e] != 0;
}

// ---------------------------------------------------------------------------
// Edge encoder MLP 7->32->16 (+ deg histogram, + sums). ea written as f16.
// raw rows staged into LDS coalesced. sums: [0..15] Σea, [16..31] Σea*mask, [32] Σmask
// ---------------------------------------------------------------------------
__global__ __launch_bounds__(256) void edge_enc(
    const float* __restrict__ raw, const int* __restrict__ ei,
    const void* __restrict__ mraw, const int* __restrict__ mflag,
    const float* __restrict__ w1, const float* __restrict__ b1,
    const float* __restrict__ w2, const float* __restrict__ b2,
    _Float16* __restrict__ ea, int* __restrict__ deg, float* __restrict__ sums, int E)
{
    __shared__ float sW1[7 * 32];
    __shared__ float sB1[32];
    __shared__ float sW2[32 * 16];
    __shared__ float sB2[16];
    __shared__ float sraw[256 * 7];
    __shared__ float red[33][4];
    int t = threadIdx.x;
    if (t < 224) sW1[t] = w1[t];
    if (t < 32)  sB1[t] = b1[t];
    for (int i = t; i < 512; i += 256) sW2[i] = w2[i];
    if (t < 16)  sB2[t] = b2[t];
    __syncthreads();
    int fl = *mflag;

    float accs[16], accm[16], cnt = 0.f;
#pragma unroll
    for (int j = 0; j < 16; ++j) { accs[j] = 0.f; accm[j] = 0.f; }

    for (int base = blockIdx.x * 256; base < E; base += gridDim.x * 256) {
        int nh = E - base; if (nh > 256) nh = 256;
        __syncthreads();
        for (int i = t; i < nh * 7; i += 256) sraw[i] = raw[(size_t)base * 7 + i];
        __syncthreads();
        int e = base + t;
        if (e < E) {
            float r[7];
#pragma unroll
            for (int k = 0; k < 7; ++k) r[k] = sraw[t * 7 + k];
            float o[16];
#pragma unroll
            for (int j = 0; j < 16; ++j) o[j] = sB2[j];
#pragma unroll
            for (int jh = 0; jh < 32; ++jh) {
                float hv = sB1[jh];
#pragma unroll
                for (int k = 0; k < 7; ++k) hv += r[k] * sW1[k * 32 + jh];
                hv = hv > 0.f ? hv : 0.f;
#pragma unroll
                for (int j = 0; j < 16; ++j) o[j] += hv * sW2[jh * 16 + j];
            }
            union { h2 h[8]; uint4 u[2]; } pk;
#pragma unroll
            for (int j = 0; j < 8; ++j) pk.h[j] = h2{(_Float16)o[2 * j], (_Float16)o[2 * j + 1]};
            uint4* dst = (uint4*)(ea + (size_t)e * 16);
            dst[0] = pk.u[0];
            dst[1] = pk.u[1];
            atomicAdd(&deg[ei[E + e]], 1);
            float mk = mask_at(mraw, fl, e) ? 1.f : 0.f;
#pragma unroll
            for (int j = 0; j < 16; ++j) { accs[j] += o[j]; accm[j] += o[j] * mk; }
            cnt += mk;
        }
    }

    int wv = t >> 6, ln = t & 63;
#pragma unroll
    for (int j = 0; j < 16; ++j) {
        float v = accs[j], vm = accm[j];
#pragma unroll
        for (int off = 32; off; off >>= 1) {
            v  += __shfl_xor(v, off, 64);
            vm += __shfl_xor(vm, off, 64);
        }
        if (ln == 0) { red[j][wv] = v; red[16 + j][wv] = vm; }
    }
    {
        float c = cnt;
#pragma unroll
        for (int off = 32; off; off >>= 1) c += __shfl_xor(c, off, 64);
        if (ln == 0) red[32][wv] = c;
    }
    __syncthreads();
    if (t < 33) {
        float v = red[t][0] + red[t][1] + red[t][2] + red[t][3];
        atomicAdd(&sums[t], v);
    }
}

// ---------------------------------------------------------------------------
// CSR build
// ---------------------------------------------------------------------------
__global__ __launch_bounds__(256) void scan1(const int* __restrict__ deg, int* __restrict__ part, int n)
{
    __shared__ int sm[256];
    int i = blockIdx.x * 256 + threadIdx.x;
    sm[threadIdx.x] = (i < n) ? deg[i] : 0;
    __syncthreads();
    for (int s = 128; s; s >>= 1) {
        if (threadIdx.x < s) sm[threadIdx.x] += sm[threadIdx.x + s];
        __syncthreads();
    }
    if (threadIdx.x == 0) part[blockIdx.x] = sm[0];
}

__global__ __launch_bounds__(256) void scan2(int* __restrict__ part, int nb)
{
    __shared__ int sm[256];
    int t = threadIdx.x;
    int v = (t < nb) ? part[t] : 0;
    sm[t] = v;
    __syncthreads();
    for (int o = 1; o < 256; o <<= 1) {
        int add = (t >= o) ? sm[t - o] : 0;
        __syncthreads();
        sm[t] += add;
        __syncthreads();
    }
    if (t < nb) part[t] = sm[t] - v;  // exclusive
}

__global__ __launch_bounds__(256) void scan3(const int* __restrict__ deg, const int* __restrict__ part,
                                             int* __restrict__ row_ofs, int* __restrict__ cursor,
                                             int n, int E)
{
    __shared__ int sm[256];
    int t = threadIdx.x;
    int i = blockIdx.x * 256 + t;
    int v = (i < n) ? deg[i] : 0;
    sm[t] = v;
    __syncthreads();
    for (int o = 1; o < 256; o <<= 1) {
        int add = (t >= o) ? sm[t - o] : 0;
        __syncthreads();
        sm[t] += add;
        __syncthreads();
    }
    int excl = sm[t] - v + part[blockIdx.x];
    if (i < n) { row_ofs[i] = excl; cursor[i] = excl; }
    if (blockIdx.x == 0 && t == 0) row_ofs[n] = E;
}

// csr entry: {e | maskbit<<31, src}
__global__ __launch_bounds__(256) void csr_fill(const int* __restrict__ ei, int* __restrict__ cursor,
                                                const void* __restrict__ mraw, const int* __restrict__ mflag,
                                                uint2* __restrict__ csr, int E)
{
    int e = blockIdx.x * 256 + threadIdx.x;
    if (e < E) {
        int fl = *mflag;
        int s = ei[e];
        int d = ei[E + e];
        int slot = atomicAdd(&cursor[d], 1);
        unsigned int v = (unsigned int)e;
        if (mask_at(mraw, fl, e)) v |= 0x80000000u;
        csr[slot] = make_uint2(v, (unsigned int)s);
    }
}

// ---------------------------------------------------------------------------
// pack_wh: Wh[256 cols][128 k] f16 (k-contiguous per col) + biasp[256] f32.
// Virtual cols: [0,96)=wl_s | [96,128)=wl_r | [128,224)=wr_s | [224,256)=wr_r
// ---------------------------------------------------------------------------
__global__ __launch_bounds__(256) void pack_wh(
    const float* __restrict__ wls, const float* __restrict__ wrs,
    const float* __restrict__ wlr, const float* __restrict__ wrr,
    const float* __restrict__ bls, const float* __restrict__ brs,
    const float* __restrict__ blr, const float* __restrict__ brr,
    _Float16* __restrict__ Wh, float* __restrict__ biasp)
{
    int idx = blockIdx.x * 256 + threadIdx.x;
    if (idx < 128 * 256) {
        int j = idx & 255, k = idx >> 8;
        float v;
        if (j < 96)       v = wls[k * 96 + j];
        else if (j < 128) v = wlr[k * 32 + (j - 96)];
        else if (j < 224) v = wrs[k * 96 + (j - 128)];
        else              v = wrr[k * 32 + (j - 224)];
        Wh[j * 128 + k] = (_Float16)v;
    }
    if (idx < 256) {
        float b;
        if (idx < 96)       b = bls[idx];
        else if (idx < 128) b = blr[idx - 96];
        else if (idx < 224) b = brs[idx - 128];
        else                b = brr[idx - 224];
        biasp[idx] = b;
    }
}

// ---------------------------------------------------------------------------
// MFMA node transforms: [64 rows x 256 cols] per block, K=128 fully in LDS.
// mfma_f32_16x16x32_f16; A/B frags = contiguous 8 f16 (k=(lane>>4)*8+j),
// C/D: col=lane&15, row=(lane>>4)*4+reg (m89). Chunk-XOR swizzle on LDS.
// ---------------------------------------------------------------------------
#define NG_BM 64
__global__ __launch_bounds__(256) void node_gemm(
    const float* __restrict__ x, const _Float16* __restrict__ Wh,
    const float* __restrict__ biasp,
    _Float16* __restrict__ XLh, float* __restrict__ XR, int n)
{
    __shared__ __align__(16) _Float16 Ash[64 * 128];    // 16 KB
    __shared__ __align__(16) _Float16 Bsh[256 * 128];   // 64 KB
    __shared__ float bsh[256];
    int tid = threadIdx.x;
    int m0 = blockIdx.x * NG_BM;

    bsh[tid] = biasp[tid];

    // stage A: 64 rows x 16 kchunks (8 f16 each), swizzled chunk = kc ^ (row&7)
    for (int c = tid; c < 64 * 16; c += 256) {
        int row = c >> 4, kc = c & 15;
        int gr = m0 + row;
        float4 a0 = make_float4(0.f, 0.f, 0.f, 0.f), a1 = a0;
        if (gr < n) {
            const float4* xp = (const float4*)(x + (size_t)gr * 128 + kc * 8);
            a0 = xp[0]; a1 = xp[1];
        }
        _Float16* dst = Ash + row * 128 + (kc ^ (row & 7)) * 8;
        dst[0] = (_Float16)a0.x; dst[1] = (_Float16)a0.y;
        dst[2] = (_Float16)a0.z; dst[3] = (_Float16)a0.w;
        dst[4] = (_Float16)a1.x; dst[5] = (_Float16)a1.y;
        dst[6] = (_Float16)a1.z; dst[7] = (_Float16)a1.w;
    }
    // stage B: 256 cols x 16 kchunks
    for (int c = tid; c < 256 * 16; c += 256) {
        int col = c >> 4, kc = c & 15;
        uint4 v = *(const uint4*)(Wh + col * 128 + kc * 8);
        *(uint4*)(Bsh + col * 128 + (kc ^ (col & 7)) * 8) = v;
    }
    __syncthreads();

    int wave = tid >> 6;
    int lane = tid & 63;
    int l16  = lane & 15;
    int lk   = lane >> 4;   // 0..3

    f32x4 acc0, acc1, acc2, acc3, acc4, acc5, acc6, acc7;
    f32x4 acc8, acc9, acc10, acc11, acc12, acc13, acc14, acc15;
    acc0 = acc1 = acc2 = acc3 = acc4 = acc5 = acc6 = acc7 = f32x4{0.f, 0.f, 0.f, 0.f};
    acc8 = acc9 = acc10 = acc11 = acc12 = acc13 = acc14 = acc15 = f32x4{0.f, 0.f, 0.f, 0.f};

#pragma unroll
    for (int kk = 0; kk < 4; ++kk) {
        int arow = wave * 16 + l16;
        f16x8 afrag = *(const f16x8*)(Ash + arow * 128 + ((kk * 4 + lk) ^ (arow & 7)) * 8);
#define BF(nt) (*(const f16x8*)(Bsh + (nt * 16 + l16) * 128 + ((kk * 4 + lk) ^ ((nt * 16 + l16) & 7)) * 8))
        acc0  = __builtin_amdgcn_mfma_f32_16x16x32_f16(afrag, BF(0),  acc0,  0, 0, 0);
        acc1  = __builtin_amdgcn_mfma_f32_16x16x32_f16(afrag, BF(1),  acc1,  0, 0, 0);
        acc2  = __builtin_amdgcn_mfma_f32_16x16x32_f16(afrag, BF(2),  acc2,  0, 0, 0);
        acc3  = __builtin_amdgcn_mfma_f32_16x16x32_f16(afrag, BF(3),  acc3,  0, 0, 0);
        acc4  = __builtin_amdgcn_mfma_f32_16x16x32_f16(afrag, BF(4),  acc4,  0, 0, 0);
        acc5  = __builtin_amdgcn_mfma_f32_16x16x32_f16(afrag, BF(5),  acc5,  0, 0, 0);
        acc6  = __builtin_amdgcn_mfma_f32_16x16x32_f16(afrag, BF(6),  acc6,  0, 0, 0);
        acc7  = __builtin_amdgcn_mfma_f32_16x16x32_f16(afrag, BF(7),  acc7,  0, 0, 0);
        acc8  = __builtin_amdgcn_mfma_f32_16x16x32_f16(afrag, BF(8),  acc8,  0, 0, 0);
        acc9  = __builtin_amdgcn_mfma_f32_16x16x32_f16(afrag, BF(9),  acc9,  0, 0, 0);
        acc10 = __builtin_amdgcn_mfma_f32_16x16x32_f16(afrag, BF(10), acc10, 0, 0, 0);
        acc11 = __builtin_amdgcn_mfma_f32_16x16x32_f16(afrag, BF(11), acc11, 0, 0, 0);
        acc12 = __builtin_amdgcn_mfma_f32_16x16x32_f16(afrag, BF(12), acc12, 0, 0, 0);
        acc13 = __builtin_amdgcn_mfma_f32_16x16x32_f16(afrag, BF(13), acc13, 0, 0, 0);
        acc14 = __builtin_amdgcn_mfma_f32_16x16x32_f16(afrag, BF(14), acc14, 0, 0, 0);
        acc15 = __builtin_amdgcn_mfma_f32_16x16x32_f16(afrag, BF(15), acc15, 0, 0, 0);
#undef BF
    }

#define STORE_ACC(nt, accv)                                             \
    {                                                                   \
        int col = nt * 16 + l16;                                        \
        float bv = bsh[col];                                            \
        _Pragma("unroll")                                               \
        for (int r = 0; r < 4; ++r) {                                   \
            int row = m0 + wave * 16 + lk * 4 + r;                      \
            if (row < n) {                                              \
                float v = accv[r] + bv;                                 \
                if (col < 128) XLh[(size_t)row * 128 + col] = (_Float16)v; \
                else           XR[(size_t)row * 128 + (col - 128)] = v; \
            }                                                           \
        }                                                               \
    }
    STORE_ACC(0, acc0)   STORE_ACC(1, acc1)   STORE_ACC(2, acc2)   STORE_ACC(3, acc3)
    STORE_ACC(4, acc4)   STORE_ACC(5, acc5)   STORE_ACC(6, acc6)   STORE_ACC(7, acc7)
    STORE_ACC(8, acc8)   STORE_ACC(9, acc9)   STORE_ACC(10, acc10) STORE_ACC(11, acc11)
    STORE_ACC(12, acc12) STORE_ACC(13, acc13) STORE_ACC(14, acc14) STORE_ACC(15, acc15)
#undef STORE_ACC
}

// ---------------------------------------------------------------------------
// One edge: gather xls, ea-dot via fdot2, leaky, group-reduce -> score.
// ---------------------------------------------------------------------------
__device__ __forceinline__ void edge_sc(
    const _Float16* __restrict__ XLh, const _Float16* __restrict__ ea,
    const uint2* __restrict__ csr, int pp, int f, bool is_std,
    float xr_n, float attv,
    h2 w0, h2 w1, h2 w2, h2 w3, h2 w4, h2 w5, h2 w6, h2 w7,
    float& s, float& x)
{
    uint2 pk = csr[pp];
    int e = __builtin_amdgcn_readfirstlane((int)(pk.x & 0x7fffffffu));
    bool act = is_std || (pk.x & 0x80000000u);
    int src = __builtin_amdgcn_readfirstlane((int)pk.y);
    x = (float)XLh[(size_t)src * 128 + f];
    union { uint4 u[2]; h2 h[8]; } pe;
    const uint4* eap = (const uint4*)(ea + (size_t)e * 16);
    pe.u[0] = eap[0]; pe.u[1] = eap[1];
    float efv = x + xr_n;
    efv = __builtin_amdgcn_fdot2(pe.h[0], w0, efv, false);
    efv = __builtin_amdgcn_fdot2(pe.h[1], w1, efv, false);
    efv = __builtin_amdgcn_fdot2(pe.h[2], w2, efv, false);
    efv = __builtin_amdgcn_fdot2(pe.h[3], w3, efv, false);
    efv = __builtin_amdgcn_fdot2(pe.h[4], w4, efv, false);
    efv = __builtin_amdgcn_fdot2(pe.h[5], w5, efv, false);
    efv = __builtin_amdgcn_fdot2(pe.h[6], w6, efv, false);
    efv = __builtin_amdgcn_fdot2(pe.h[7], w7, efv, false);
    float lk = fmaxf(efv, NEG_SLOPE * efv);
    float sv = grp32_sum(lk * attv);
    s = act ? sv : -INFINITY;
}

// ---------------------------------------------------------------------------
// Fused GATv2: one 128-thread block per node, lane = output feature.
// ---------------------------------------------------------------------------
__global__ __launch_bounds__(128, 4) void gat_main(
    const _Float16* __restrict__ XLh, const float* __restrict__ XR,
    const _Float16* __restrict__ ea, const uint2* __restrict__ csr,
    const int* __restrict__ row_ofs,
    const float* __restrict__ sums,
    const float* __restrict__ we_s, const float* __restrict__ we_r,
    const float* __restrict__ att_s, const float* __restrict__ att_r,
    const float* __restrict__ bias_s, const float* __restrict__ bias_r,
    float* __restrict__ out, int n, int E)
{
    int node = blockIdx.x;
    int f = threadIdx.x;
    bool is_std = f < OUT_STD;

    const float* wsrc = is_std ? we_s : we_r;
    int ldw = is_std ? OUT_STD : OUT_REP;
    int fc  = is_std ? f : (f - OUT_STD);
    const float* sp = is_std ? sums : (sums + 16);
    float c = sums[32]; c = c < 1.f ? 1.f : c;
    float scl = is_std ? (1.f / (float)E) : (1.f / c);

    float efl;
    h2 w0, w1, w2, w3, w4, w5, w6, w7;
    {
        float v0, v1;
#define LOADW(dst, k0, k1)                                           \
        v0 = wsrc[(k0) * ldw + fc]; v1 = wsrc[(k1) * ldw + fc];      \
        dst = h2{(_Float16)v0, (_Float16)v1};                        \
        efl += sp[k0] * scl * v0 + sp[k1] * scl * v1;
        efl = 0.f;
        LOADW(w0, 0, 1)   LOADW(w1, 2, 3)
        LOADW(w2, 4, 5)   LOADW(w3, 6, 7)
        LOADW(w4, 8, 9)   LOADW(w5, 10, 11)
        LOADW(w6, 12, 13) LOADW(w7, 14, 15)
#undef LOADW
    }

    float attv  = (is_std ? att_s[f] : att_r[fc]) * LOG2E;
    float biasv = is_std ? bias_s[f] : bias_r[fc];

    float xl_n = (float)XLh[(size_t)node * 128 + f];
    float xr_n = XR[(size_t)node * 128 + f];

    float msg = xl_n + xr_n + efl;
    float lk0 = fmaxf(msg, NEG_SLOPE * msg);
    float m = grp32_sum(lk0 * attv);
    float denom = 1.f, acc = xl_n;

    int p0 = row_ofs[node], p1 = row_ofs[node + 1];
    int p = p0;
    for (; p + 8 <= p1; p += 8) {
        float s0, s1, s2, s3, s4, s5, s6, s7;
        float x0, x1, x2, x3, x4, x5, x6, x7;
        edge_sc(XLh, ea, csr, p + 0, f, is_std, xr_n, attv, w0, w1, w2, w3, w4, w5, w6, w7, s0, x0);
        edge_sc(XLh, ea, csr, p + 1, f, is_std, xr_n, attv, w0, w1, w2, w3, w4, w5, w6, w7, s1, x1);
        edge_sc(XLh, ea, csr, p + 2, f, is_std, xr_n, attv, w0, w1, w2, w3, w4, w5, w6, w7, s2, x2);
        edge_sc(XLh, ea, csr, p + 3, f, is_std, xr_n, attv, w0, w1, w2, w3, w4, w5, w6, w7, s3, x3);
        edge_sc(XLh, ea, csr, p + 4, f, is_std, xr_n, attv, w0, w1, w2, w3, w4, w5, w6, w7, s4, x4);
        edge_sc(XLh, ea, csr, p + 5, f, is_std, xr_n, attv, w0, w1, w2, w3, w4, w5, w6, w7, s5, x5);
        edge_sc(XLh, ea, csr, p + 6, f, is_std, xr_n, attv, w0, w1, w2, w3, w4, w5, w6, w7, s6, x6);
        edge_sc(XLh, ea, csr, p + 7, f, is_std, xr_n, attv, w0, w1, w2, w3, w4, w5, w6, w7, s7, x7);

        float mn = fmaxf(m, fmaxf(fmaxf(fmaxf(s0, s1), fmaxf(s2, s3)),
                                  fmaxf(fmaxf(s4, s5), fmaxf(s6, s7))));
        float r  = exp2f(m - mn);
        float q0 = exp2f(s0 - mn), q1 = exp2f(s1 - mn);
        float q2 = exp2f(s2 - mn), q3 = exp2f(s3 - mn);
        float q4 = exp2f(s4 - mn), q5 = exp2f(s5 - mn);
        float q6 = exp2f(s6 - mn), q7 = exp2f(s7 - mn);
        denom = denom * r + (((q0 + q1) + (q2 + q3)) + ((q4 + q5) + (q6 + q7)));
        acc   = acc * r + (((q0 * x0 + q1 * x1) + (q2 * x2 + q3 * x3))
                         + ((q4 * x4 + q5 * x5) + (q6 * x6 + q7 * x7)));
        m = mn;
    }
    for (; p < p1; ++p) {
        float s8, x8;
        edge_sc(XLh, ea, csr, p, f, is_std, xr_n, attv, w0, w1, w2, w3, w4, w5, w6, w7, s8, x8);
        float mn = fmaxf(m, s8);
        float r  = exp2f(m - mn);
        float q  = exp2f(s8 - mn);
        denom = denom * r + q;
        acc   = acc * r + q * x8;
        m = mn;
    }
    out[(size_t)node * OUT_ALL + f] = acc / denom + biasv;
}

// ---------------------------------------------------------------------------
extern "C" void kernel_launch(void* const* d_in, const int* in_sizes, int n_in,
                              void* d_out, int out_size, void* d_ws, size_t ws_size,
                              hipStream_t stream)
{
    const float* x    = (const float*)d_in[0];
    const float* raw  = (const float*)d_in[1];
    const int*   ei   = (const int*)d_in[2];
    const void*  mask_raw = d_in[3];
    const float* ee_w1 = (const float*)d_in[4];
    const float* ee_b1 = (const float*)d_in[5];
    const float* ee_w2 = (const float*)d_in[6];
    const float* ee_b2 = (const float*)d_in[7];
    const float* wl_s = (const float*)d_in[8];
    const float* bl_s = (const float*)d_in[9];
    const float* wr_s = (const float*)d_in[10];
    const float* br_s = (const float*)d_in[11];
    const float* we_s = (const float*)d_in[12];
    const float* att_s = (const float*)d_in[13];
    const float* bias_s = (const float*)d_in[14];
    const float* wl_r = (const float*)d_in[15];
    const float* bl_r = (const float*)d_in[16];
    const float* wr_r = (const float*)d_in[17];
    const float* br_r = (const float*)d_in[18];
    const float* we_r = (const float*)d_in[19];
    const float* att_r = (const float*)d_in[20];
    const float* bias_r = (const float*)d_in[21];

    const int N = in_sizes[0] / IN_DIM;
    const int E = in_sizes[1] / 7;

    char* w = (char*)d_ws;
    size_t off = 0;
    auto carve = [&](size_t bytes) {
        void* p = w + off;
        off = (off + bytes + 255) & ~(size_t)255;
        return p;
    };
    _Float16* XLh  = (_Float16*)carve((size_t)N * 128 * 2);
    float* XR      = (float*)carve((size_t)N * 128 * 4);
    _Float16* ea   = (_Float16*)carve((size_t)E * 16 * 2);
    uint2* csr     = (uint2*)carve((size_t)E * 8);
    int*   row_ofs = (int*)carve((size_t)(N + 1) * 4);
    int*   cursor  = (int*)carve((size_t)N * 4);
    int*   deg     = (int*)carve((size_t)N * 4);
    int*   part    = (int*)carve(1024);
    float* sums    = (float*)carve(256);
    _Float16* Wh   = (_Float16*)carve((size_t)256 * 128 * 2);
    float* biasp   = (float*)carve(1024);
    int*   mflag   = (int*)carve(256);
    (void)ws_size; (void)n_in; (void)out_size;

    hipMemsetAsync(deg, 0, (size_t)N * 4, stream);
    hipMemsetAsync(sums, 0, 256, stream);

    int ebl = (E + 255) / 256;
    int nbl = (N + 255) / 256;

    int nprobe = E < 4096 ? E : 4096;
    mask_detect<<<1, 64, 0, stream>>>((const unsigned char*)mask_raw, mflag, nprobe);

    int eebl = ebl < EE_BLOCKS ? ebl : EE_BLOCKS;
    edge_enc<<<eebl, 256, 0, stream>>>(raw, ei, mask_raw, mflag, ee_w1, ee_b1, ee_w2, ee_b2, ea, deg, sums, E);
    scan1<<<nbl, 256, 0, stream>>>(deg, part, N);
    scan2<<<1, 256, 0, stream>>>(part, nbl);
    scan3<<<nbl, 256, 0, stream>>>(deg, part, row_ofs, cursor, N, E);
    csr_fill<<<ebl, 256, 0, stream>>>(ei, cursor, mask_raw, mflag, csr, E);
    pack_wh<<<128, 256, 0, stream>>>(wl_s, wr_s, wl_r, wr_r, bl_s, br_s, bl_r, br_r, Wh, biasp);
    node_gemm<<<(N + NG_BM - 1) / NG_BM, 256, 0, stream>>>(x, Wh, biasp, XLh, XR, N);
    gat_main<<<N, 128, 0, stream>>>(XLh, XR, ea, csr, row_ofs, sums,
                                    we_s, we_r, att_s, att_r, bias_s, bias_r,
                                    (float*)d_out, N, E);
}

// Round 13
// 273.035 us; speedup vs baseline: 1.3954x; 1.1476x over previous
//
#include <hip/hip_runtime.h>
#include <hip/hip_bf16.h>
#include <cstdint>

#define IN_DIM 128
#define OUT_STD 96
#define OUT_REP 32
#define OUT_ALL 128
#define NEG_SLOPE 0.2f
#define EE_BLOCKS 512
#define LOG2E 1.4426950408889634f

typedef _Float16 h2 __attribute__((ext_vector_type(2)));
typedef _Float16 f16x8 __attribute__((ext_vector_type(8)));
typedef float f32x4 __attribute__((ext_vector_type(4)));

// 32-lane group sum: 4 DPP stages (VALU) + one xor-16 ds_swizzle.
template <int CTRL>
__device__ __forceinline__ float dpp_add(float v)
{
    int x = __builtin_amdgcn_update_dpp(0, __float_as_int(v), CTRL, 0xf, 0xf, true);
    return v + __int_as_float(x);
}
__device__ __forceinline__ float grp32_sum(float v)
{
    v = dpp_add<0xB1>(v);   // quad_perm xor1
    v = dpp_add<0x4E>(v);   // quad_perm xor2
    v = dpp_add<0x141>(v);  // row_half_mirror (xor4)
    v = dpp_add<0x140>(v);  // row_mirror (xor8)
    int x = __builtin_amdgcn_ds_swizzle(__float_as_int(v), 0x401F); // xor16 within 32
    return v + __int_as_float(x);
}

// ---------------------------------------------------------------------------
// Per-block mask dtype detection (JAX bool may arrive as uint8 / int32 / f32).
// Deterministic: every block scans the same first nprobe bytes.
// fl: 2=f32, 1=int32, 0=uint8
// ---------------------------------------------------------------------------
__device__ __forceinline__ int detect_mask_fl(const void* mraw, int nprobe, int* sfl)
{
    int t = threadIdx.x;
    const unsigned char* mb = (const unsigned char*)mraw;
    int anyGT1 = 0, any123 = 0;
    for (int i = t; i < nprobe; i += 256) {
        unsigned char b = mb[i];
        if (b > 1) anyGT1 = 1;
        if ((i & 3) && b) any123 = 1;
    }
    anyGT1 = __any(anyGT1);
    any123 = __any(any123);
    if (t == 0) *sfl = 0;
    __syncthreads();
    if ((t & 63) == 0) atomicOr(sfl, (anyGT1 ? 2 : 0) | (any123 ? 1 : 0));
    __syncthreads();
    int v = *sfl;
    return (v & 2) ? 2 : ((v & 1) ? 0 : 1);
}

__device__ __forceinline__ bool mask_at(const void* m, int fl, int e)
{
    if (fl == 1) return ((const int*)m)[e] != 0;
    if (fl == 2) return ((const float*)m)[e] != 0.f;
    return ((const unsigned char*)m)[e] != 0;
}

// ---------------------------------------------------------------------------
// Edge encoder MLP 7->32->16 (+ deg histogram, + sums). ea written as f16.
// sums: [0..15] Σea, [16..31] Σea*mask, [32] Σmask
// ---------------------------------------------------------------------------
__global__ __launch_bounds__(256) void edge_enc(
    const float* __restrict__ raw, const int* __restrict__ ei,
    const void* __restrict__ mraw, int nprobe,
    const float* __restrict__ w1, const float* __restrict__ b1,
    const float* __restrict__ w2, const float* __restrict__ b2,
    _Float16* __restrict__ ea, int* __restrict__ deg, float* __restrict__ sums, int E)
{
    __shared__ float sW1[7 * 32];
    __shared__ float sB1[32];
    __shared__ float sW2[32 * 16];
    __shared__ float sB2[16];
    __shared__ float sraw[256 * 7];
    __shared__ float red[33][4];
    __shared__ int sfl;
    int t = threadIdx.x;
    int fl = detect_mask_fl(mraw, nprobe, &sfl);
    if (t < 224) sW1[t] = w1[t];
    if (t < 32)  sB1[t] = b1[t];
    for (int i = t; i < 512; i += 256) sW2[i] = w2[i];
    if (t < 16)  sB2[t] = b2[t];
    __syncthreads();

    float accs[16], accm[16], cnt = 0.f;
#pragma unroll
    for (int j = 0; j < 16; ++j) { accs[j] = 0.f; accm[j] = 0.f; }

    for (int base = blockIdx.x * 256; base < E; base += gridDim.x * 256) {
        int nh = E - base; if (nh > 256) nh = 256;
        __syncthreads();
        for (int i = t; i < nh * 7; i += 256) sraw[i] = raw[(size_t)base * 7 + i];
        __syncthreads();
        int e = base + t;
        if (e < E) {
            float r[7];
#pragma unroll
            for (int k = 0; k < 7; ++k) r[k] = sraw[t * 7 + k];
            float o[16];
#pragma unroll
            for (int j = 0; j < 16; ++j) o[j] = sB2[j];
#pragma unroll
            for (int jh = 0; jh < 32; ++jh) {
                float hv = sB1[jh];
#pragma unroll
                for (int k = 0; k < 7; ++k) hv += r[k] * sW1[k * 32 + jh];
                hv = hv > 0.f ? hv : 0.f;
#pragma unroll
                for (int j = 0; j < 16; ++j) o[j] += hv * sW2[jh * 16 + j];
            }
            union { h2 h[8]; uint4 u[2]; } pk;
#pragma unroll
            for (int j = 0; j < 8; ++j) pk.h[j] = h2{(_Float16)o[2 * j], (_Float16)o[2 * j + 1]};
            uint4* dst = (uint4*)(ea + (size_t)e * 16);
            dst[0] = pk.u[0];
            dst[1] = pk.u[1];
            atomicAdd(&deg[ei[E + e]], 1);
            float mk = mask_at(mraw, fl, e) ? 1.f : 0.f;
#pragma unroll
            for (int j = 0; j < 16; ++j) { accs[j] += o[j]; accm[j] += o[j] * mk; }
            cnt += mk;
        }
    }

    int wv = t >> 6, ln = t & 63;
#pragma unroll
    for (int j = 0; j < 16; ++j) {
        float v = accs[j], vm = accm[j];
#pragma unroll
        for (int off = 32; off; off >>= 1) {
            v  += __shfl_xor(v, off, 64);
            vm += __shfl_xor(vm, off, 64);
        }
        if (ln == 0) { red[j][wv] = v; red[16 + j][wv] = vm; }
    }
    {
        float c = cnt;
#pragma unroll
        for (int off = 32; off; off >>= 1) c += __shfl_xor(c, off, 64);
        if (ln == 0) red[32][wv] = c;
    }
    __syncthreads();
    if (t < 33) {
        float v = red[t][0] + red[t][1] + red[t][2] + red[t][3];
        atomicAdd(&sums[t], v);
    }
}

// ---------------------------------------------------------------------------
// CSR build: scan1 (block totals) + scan23 (prefix + local scan fused)
// ---------------------------------------------------------------------------
__global__ __launch_bounds__(256) void scan1(const int* __restrict__ deg, int* __restrict__ part, int n)
{
    __shared__ int sm[256];
    int i = blockIdx.x * 256 + threadIdx.x;
    sm[threadIdx.x] = (i < n) ? deg[i] : 0;
    __syncthreads();
    for (int s = 128; s; s >>= 1) {
        if (threadIdx.x < s) sm[threadIdx.x] += sm[threadIdx.x + s];
        __syncthreads();
    }
    if (threadIdx.x == 0) part[blockIdx.x] = sm[0];
}

// requires gridDim.x (== nbl) <= 256
__global__ __launch_bounds__(256) void scan23(const int* __restrict__ deg, const int* __restrict__ part,
                                              int* __restrict__ row_ofs, int* __restrict__ cursor,
                                              int n, int E, int nbl)
{
    __shared__ int sm[256];
    __shared__ int spre;
    int t = threadIdx.x, b = blockIdx.x;
    // prefix = sum part[0..b)
    sm[t] = (t < b) ? part[t] : 0;
    __syncthreads();
    for (int s = 128; s; s >>= 1) {
        if (t < s) sm[t] += sm[t + s];
        __syncthreads();
    }
    if (t == 0) spre = sm[0];
    __syncthreads();
    int prefix = spre;
    __syncthreads();
    // local inclusive scan of this block's segment
    int i = b * 256 + t;
    int v = (i < n) ? deg[i] : 0;
    sm[t] = v;
    __syncthreads();
    for (int o = 1; o < 256; o <<= 1) {
        int add = (t >= o) ? sm[t - o] : 0;
        __syncthreads();
        sm[t] += add;
        __syncthreads();
    }
    int excl = sm[t] - v + prefix;
    if (i < n) { row_ofs[i] = excl; cursor[i] = excl; }
    if (b == 0 && t == 0) row_ofs[n] = E;
}

// csr entry: {e | maskbit<<31, src}
__global__ __launch_bounds__(256) void csr_fill(const int* __restrict__ ei, int* __restrict__ cursor,
                                                const void* __restrict__ mraw, int nprobe,
                                                uint2* __restrict__ csr, int E)
{
    __shared__ int sfl;
    int fl = detect_mask_fl(mraw, nprobe, &sfl);
    int e = blockIdx.x * 256 + threadIdx.x;
    if (e < E) {
        int s = ei[e];
        int d = ei[E + e];
        int slot = atomicAdd(&cursor[d], 1);
        unsigned int v = (unsigned int)e;
        if (mask_at(mraw, fl, e)) v |= 0x80000000u;
        csr[slot] = make_uint2(v, (unsigned int)s);
    }
}

// ---------------------------------------------------------------------------
// pack_wh + prep: blocks 0..127 pack Wh[256][128] f16 + biasp[256] f32;
// block 128 precomputes gat_main per-feature constants:
//   wpk[128][16] f16 (we column per output feature), eflv/attvv/biasvv[128]
// ---------------------------------------------------------------------------
__global__ __launch_bounds__(256) void pack_wh(
    const float* __restrict__ wls, const float* __restrict__ wrs,
    const float* __restrict__ wlr, const float* __restrict__ wrr,
    const float* __restrict__ bls, const float* __restrict__ brs,
    const float* __restrict__ blr, const float* __restrict__ brr,
    const float* __restrict__ we_s, const float* __restrict__ we_r,
    const float* __restrict__ att_s, const float* __restrict__ att_r,
    const float* __restrict__ bias_s, const float* __restrict__ bias_r,
    const float* __restrict__ sums, int E,
    _Float16* __restrict__ Wh, float* __restrict__ biasp,
    _Float16* __restrict__ wpk, float* __restrict__ eflv,
    float* __restrict__ attvv, float* __restrict__ biasvv)
{
    if (blockIdx.x == 128) {
        int t = threadIdx.x;
        if (t < 128) {
            bool is_std = t < OUT_STD;
            int fc = is_std ? t : (t - OUT_STD);
            const float* wsrc = is_std ? we_s : we_r;
            int ldw = is_std ? OUT_STD : OUT_REP;
            const float* sp = is_std ? sums : (sums + 16);
            float c = sums[32]; c = c < 1.f ? 1.f : c;
            float scl = is_std ? (1.f / (float)E) : (1.f / c);
            float efl = 0.f;
#pragma unroll
            for (int k = 0; k < 16; ++k) {
                float v = wsrc[k * ldw + fc];
                wpk[t * 16 + k] = (_Float16)v;
                efl += sp[k] * scl * v;
            }
            eflv[t] = efl;
            attvv[t] = (is_std ? att_s[t] : att_r[fc]) * LOG2E;
            biasvv[t] = is_std ? bias_s[t] : bias_r[fc];
        }
        return;
    }
    int idx = blockIdx.x * 256 + threadIdx.x;
    if (idx < 128 * 256) {
        int j = idx & 255, k = idx >> 8;
        float v;
        if (j < 96)       v = wls[k * 96 + j];
        else if (j < 128) v = wlr[k * 32 + (j - 96)];
        else if (j < 224) v = wrs[k * 96 + (j - 128)];
        else              v = wrr[k * 32 + (j - 224)];
        Wh[j * 128 + k] = (_Float16)v;
    }
    if (idx < 256) {
        float b;
        if (idx < 96)       b = bls[idx];
        else if (idx < 128) b = blr[idx - 96];
        else if (idx < 224) b = brs[idx - 128];
        else                b = brr[idx - 224];
        biasp[idx] = b;
    }
}

// ---------------------------------------------------------------------------
// MFMA node transforms: [64 rows x 256 cols] per block, K=128 fully in LDS.
// ---------------------------------------------------------------------------
#define NG_BM 64
__global__ __launch_bounds__(256) void node_gemm(
    const float* __restrict__ x, const _Float16* __restrict__ Wh,
    const float* __restrict__ biasp,
    _Float16* __restrict__ XLh, float* __restrict__ XR, int n)
{
    __shared__ __align__(16) _Float16 Ash[64 * 128];    // 16 KB
    __shared__ __align__(16) _Float16 Bsh[256 * 128];   // 64 KB
    __shared__ float bsh[256];
    int tid = threadIdx.x;
    int m0 = blockIdx.x * NG_BM;

    bsh[tid] = biasp[tid];

    for (int c = tid; c < 64 * 16; c += 256) {
        int row = c >> 4, kc = c & 15;
        int gr = m0 + row;
        float4 a0 = make_float4(0.f, 0.f, 0.f, 0.f), a1 = a0;
        if (gr < n) {
            const float4* xp = (const float4*)(x + (size_t)gr * 128 + kc * 8);
            a0 = xp[0]; a1 = xp[1];
        }
        _Float16* dst = Ash + row * 128 + (kc ^ (row & 7)) * 8;
        dst[0] = (_Float16)a0.x; dst[1] = (_Float16)a0.y;
        dst[2] = (_Float16)a0.z; dst[3] = (_Float16)a0.w;
        dst[4] = (_Float16)a1.x; dst[5] = (_Float16)a1.y;
        dst[6] = (_Float16)a1.z; dst[7] = (_Float16)a1.w;
    }
    for (int c = tid; c < 256 * 16; c += 256) {
        int col = c >> 4, kc = c & 15;
        uint4 v = *(const uint4*)(Wh + col * 128 + kc * 8);
        *(uint4*)(Bsh + col * 128 + (kc ^ (col & 7)) * 8) = v;
    }
    __syncthreads();

    int wave = tid >> 6;
    int lane = tid & 63;
    int l16  = lane & 15;
    int lk   = lane >> 4;

    f32x4 acc0, acc1, acc2, acc3, acc4, acc5, acc6, acc7;
    f32x4 acc8, acc9, acc10, acc11, acc12, acc13, acc14, acc15;
    acc0 = acc1 = acc2 = acc3 = acc4 = acc5 = acc6 = acc7 = f32x4{0.f, 0.f, 0.f, 0.f};
    acc8 = acc9 = acc10 = acc11 = acc12 = acc13 = acc14 = acc15 = f32x4{0.f, 0.f, 0.f, 0.f};

#pragma unroll
    for (int kk = 0; kk < 4; ++kk) {
        int arow = wave * 16 + l16;
        f16x8 afrag = *(const f16x8*)(Ash + arow * 128 + ((kk * 4 + lk) ^ (arow & 7)) * 8);
#define BF(nt) (*(const f16x8*)(Bsh + (nt * 16 + l16) * 128 + ((kk * 4 + lk) ^ ((nt * 16 + l16) & 7)) * 8))
        acc0  = __builtin_amdgcn_mfma_f32_16x16x32_f16(afrag, BF(0),  acc0,  0, 0, 0);
        acc1  = __builtin_amdgcn_mfma_f32_16x16x32_f16(afrag, BF(1),  acc1,  0, 0, 0);
        acc2  = __builtin_amdgcn_mfma_f32_16x16x32_f16(afrag, BF(2),  acc2,  0, 0, 0);
        acc3  = __builtin_amdgcn_mfma_f32_16x16x32_f16(afrag, BF(3),  acc3,  0, 0, 0);
        acc4  = __builtin_amdgcn_mfma_f32_16x16x32_f16(afrag, BF(4),  acc4,  0, 0, 0);
        acc5  = __builtin_amdgcn_mfma_f32_16x16x32_f16(afrag, BF(5),  acc5,  0, 0, 0);
        acc6  = __builtin_amdgcn_mfma_f32_16x16x32_f16(afrag, BF(6),  acc6,  0, 0, 0);
        acc7  = __builtin_amdgcn_mfma_f32_16x16x32_f16(afrag, BF(7),  acc7,  0, 0, 0);
        acc8  = __builtin_amdgcn_mfma_f32_16x16x32_f16(afrag, BF(8),  acc8,  0, 0, 0);
        acc9  = __builtin_amdgcn_mfma_f32_16x16x32_f16(afrag, BF(9),  acc9,  0, 0, 0);
        acc10 = __builtin_amdgcn_mfma_f32_16x16x32_f16(afrag, BF(10), acc10, 0, 0, 0);
        acc11 = __builtin_amdgcn_mfma_f32_16x16x32_f16(afrag, BF(11), acc11, 0, 0, 0);
        acc12 = __builtin_amdgcn_mfma_f32_16x16x32_f16(afrag, BF(12), acc12, 0, 0, 0);
        acc13 = __builtin_amdgcn_mfma_f32_16x16x32_f16(afrag, BF(13), acc13, 0, 0, 0);
        acc14 = __builtin_amdgcn_mfma_f32_16x16x32_f16(afrag, BF(14), acc14, 0, 0, 0);
        acc15 = __builtin_amdgcn_mfma_f32_16x16x32_f16(afrag, BF(15), acc15, 0, 0, 0);
#undef BF
    }

#define STORE_ACC(nt, accv)                                             \
    {                                                                   \
        int col = nt * 16 + l16;                                        \
        float bv = bsh[col];                                            \
        _Pragma("unroll")                                               \
        for (int r = 0; r < 4; ++r) {                                   \
            int row = m0 + wave * 16 + lk * 4 + r;                      \
            if (row < n) {                                              \
                float v = accv[r] + bv;                                 \
                if (col < 128) XLh[(size_t)row * 128 + col] = (_Float16)v; \
                else           XR[(size_t)row * 128 + (col - 128)] = v; \
            }                                                           \
        }                                                               \
    }
    STORE_ACC(0, acc0)   STORE_ACC(1, acc1)   STORE_ACC(2, acc2)   STORE_ACC(3, acc3)
    STORE_ACC(4, acc4)   STORE_ACC(5, acc5)   STORE_ACC(6, acc6)   STORE_ACC(7, acc7)
    STORE_ACC(8, acc8)   STORE_ACC(9, acc9)   STORE_ACC(10, acc10) STORE_ACC(11, acc11)
    STORE_ACC(12, acc12) STORE_ACC(13, acc13) STORE_ACC(14, acc14) STORE_ACC(15, acc15)
#undef STORE_ACC
}

// ---------------------------------------------------------------------------
// One edge: gather xls, ea-dot via fdot2, leaky, group-reduce -> score.
// ---------------------------------------------------------------------------
__device__ __forceinline__ void edge_sc(
    const _Float16* __restrict__ XLh, const _Float16* __restrict__ ea,
    const uint2* __restrict__ csr, int pp, int f, bool is_std,
    float xr_n, float attv,
    h2 w0, h2 w1, h2 w2, h2 w3, h2 w4, h2 w5, h2 w6, h2 w7,
    float& s, float& x)
{
    uint2 pk = csr[pp];
    int e = __builtin_amdgcn_readfirstlane((int)(pk.x & 0x7fffffffu));
    bool act = is_std || (pk.x & 0x80000000u);
    int src = __builtin_amdgcn_readfirstlane((int)pk.y);
    x = (float)XLh[(size_t)src * 128 + f];
    union { uint4 u[2]; h2 h[8]; } pe;
    const uint4* eap = (const uint4*)(ea + (size_t)e * 16);
    pe.u[0] = eap[0]; pe.u[1] = eap[1];
    float efv = x + xr_n;
    efv = __builtin_amdgcn_fdot2(pe.h[0], w0, efv, false);
    efv = __builtin_amdgcn_fdot2(pe.h[1], w1, efv, false);
    efv = __builtin_amdgcn_fdot2(pe.h[2], w2, efv, false);
    efv = __builtin_amdgcn_fdot2(pe.h[3], w3, efv, false);
    efv = __builtin_amdgcn_fdot2(pe.h[4], w4, efv, false);
    efv = __builtin_amdgcn_fdot2(pe.h[5], w5, efv, false);
    efv = __builtin_amdgcn_fdot2(pe.h[6], w6, efv, false);
    efv = __builtin_amdgcn_fdot2(pe.h[7], w7, efv, false);
    float lk = fmaxf(efv, NEG_SLOPE * efv);
    float sv = grp32_sum(lk * attv);
    s = act ? sv : -INFINITY;
}

// ---------------------------------------------------------------------------
// Fused GATv2: one 128-thread block per node, lane = output feature.
// ---------------------------------------------------------------------------
__global__ __launch_bounds__(128, 4) void gat_main(
    const _Float16* __restrict__ XLh, const float* __restrict__ XR,
    const _Float16* __restrict__ ea, const uint2* __restrict__ csr,
    const int* __restrict__ row_ofs,
    const _Float16* __restrict__ wpk, const float* __restrict__ eflv,
    const float* __restrict__ attvv, const float* __restrict__ biasvv,
    float* __restrict__ out, int n)
{
    int node = blockIdx.x;
    int f = threadIdx.x;
    bool is_std = f < OUT_STD;

    union { uint4 u; h2 h[4]; } c0, c1;
    const uint4* wp = (const uint4*)(wpk + (size_t)f * 16);
    c0.u = wp[0]; c1.u = wp[1];
    h2 w0 = c0.h[0], w1 = c0.h[1], w2 = c0.h[2], w3 = c0.h[3];
    h2 w4 = c1.h[0], w5 = c1.h[1], w6 = c1.h[2], w7 = c1.h[3];

    float efl   = eflv[f];
    float attv  = attvv[f];
    float biasv = biasvv[f];

    float xl_n = (float)XLh[(size_t)node * 128 + f];
    float xr_n = XR[(size_t)node * 128 + f];

    float msg = xl_n + xr_n + efl;
    float lk0 = fmaxf(msg, NEG_SLOPE * msg);
    float m = grp32_sum(lk0 * attv);
    float denom = 1.f, acc = xl_n;

    int p0 = row_ofs[node], p1 = row_ofs[node + 1];
    int p = p0;
    for (; p + 8 <= p1; p += 8) {
        float s0, s1, s2, s3, s4, s5, s6, s7;
        float x0, x1, x2, x3, x4, x5, x6, x7;
        edge_sc(XLh, ea, csr, p + 0, f, is_std, xr_n, attv, w0, w1, w2, w3, w4, w5, w6, w7, s0, x0);
        edge_sc(XLh, ea, csr, p + 1, f, is_std, xr_n, attv, w0, w1, w2, w3, w4, w5, w6, w7, s1, x1);
        edge_sc(XLh, ea, csr, p + 2, f, is_std, xr_n, attv, w0, w1, w2, w3, w4, w5, w6, w7, s2, x2);
        edge_sc(XLh, ea, csr, p + 3, f, is_std, xr_n, attv, w0, w1, w2, w3, w4, w5, w6, w7, s3, x3);
        edge_sc(XLh, ea, csr, p + 4, f, is_std, xr_n, attv, w0, w1, w2, w3, w4, w5, w6, w7, s4, x4);
        edge_sc(XLh, ea, csr, p + 5, f, is_std, xr_n, attv, w0, w1, w2, w3, w4, w5, w6, w7, s5, x5);
        edge_sc(XLh, ea, csr, p + 6, f, is_std, xr_n, attv, w0, w1, w2, w3, w4, w5, w6, w7, s6, x6);
        edge_sc(XLh, ea, csr, p + 7, f, is_std, xr_n, attv, w0, w1, w2, w3, w4, w5, w6, w7, s7, x7);

        float mn = fmaxf(m, fmaxf(fmaxf(fmaxf(s0, s1), fmaxf(s2, s3)),
                                  fmaxf(fmaxf(s4, s5), fmaxf(s6, s7))));
        float r  = exp2f(m - mn);
        float q0 = exp2f(s0 - mn), q1 = exp2f(s1 - mn);
        float q2 = exp2f(s2 - mn), q3 = exp2f(s3 - mn);
        float q4 = exp2f(s4 - mn), q5 = exp2f(s5 - mn);
        float q6 = exp2f(s6 - mn), q7 = exp2f(s7 - mn);
        denom = denom * r + (((q0 + q1) + (q2 + q3)) + ((q4 + q5) + (q6 + q7)));
        acc   = acc * r + (((q0 * x0 + q1 * x1) + (q2 * x2 + q3 * x3))
                         + ((q4 * x4 + q5 * x5) + (q6 * x6 + q7 * x7)));
        m = mn;
    }
    for (; p < p1; ++p) {
        float s8, x8;
        edge_sc(XLh, ea, csr, p, f, is_std, xr_n, attv, w0, w1, w2, w3, w4, w5, w6, w7, s8, x8);
        float mn = fmaxf(m, s8);
        float r  = exp2f(m - mn);
        float q  = exp2f(s8 - mn);
        denom = denom * r + q;
        acc   = acc * r + q * x8;
        m = mn;
    }
    out[(size_t)node * OUT_ALL + f] = acc / denom + biasv;
}

// ---------------------------------------------------------------------------
extern "C" void kernel_launch(void* const* d_in, const int* in_sizes, int n_in,
                              void* d_out, int out_size, void* d_ws, size_t ws_size,
                              hipStream_t stream)
{
    const float* x    = (const float*)d_in[0];
    const float* raw  = (const float*)d_in[1];
    const int*   ei   = (const int*)d_in[2];
    const void*  mask_raw = d_in[3];
    const float* ee_w1 = (const float*)d_in[4];
    const float* ee_b1 = (const float*)d_in[5];
    const float* ee_w2 = (const float*)d_in[6];
    const float* ee_b2 = (const float*)d_in[7];
    const float* wl_s = (const float*)d_in[8];
    const float* bl_s = (const float*)d_in[9];
    const float* wr_s = (const float*)d_in[10];
    const float* br_s = (const float*)d_in[11];
    const float* we_s = (const float*)d_in[12];
    const float* att_s = (const float*)d_in[13];
    const float* bias_s = (const float*)d_in[14];
    const float* wl_r = (const float*)d_in[15];
    const float* bl_r = (const float*)d_in[16];
    const float* wr_r = (const float*)d_in[17];
    const float* br_r = (const float*)d_in[18];
    const float* we_r = (const float*)d_in[19];
    const float* att_r = (const float*)d_in[20];
    const float* bias_r = (const float*)d_in[21];

    const int N = in_sizes[0] / IN_DIM;
    const int E = in_sizes[1] / 7;

    char* w = (char*)d_ws;
    size_t off = 0;
    auto carve = [&](size_t bytes) {
        void* p = w + off;
        off = (off + bytes + 255) & ~(size_t)255;
        return p;
    };
    _Float16* XLh  = (_Float16*)carve((size_t)N * 128 * 2);
    float* XR      = (float*)carve((size_t)N * 128 * 4);
    _Float16* ea   = (_Float16*)carve((size_t)E * 16 * 2);
    uint2* csr     = (uint2*)carve((size_t)E * 8);
    int*   row_ofs = (int*)carve((size_t)(N + 1) * 4);
    int*   cursor  = (int*)carve((size_t)N * 4);
    int*   deg     = (int*)carve((size_t)N * 4);
    int*   part    = (int*)carve(1024);
    float* sums    = (float*)carve(256);
    _Float16* Wh   = (_Float16*)carve((size_t)256 * 128 * 2);
    float* biasp   = (float*)carve(1024);
    _Float16* wpk  = (_Float16*)carve((size_t)128 * 16 * 2);
    float* eflv    = (float*)carve(512);
    float* attvv   = (float*)carve(512);
    float* biasvv  = (float*)carve(512);
    (void)ws_size; (void)n_in; (void)out_size;

    hipMemsetAsync(deg, 0, (size_t)N * 4, stream);
    hipMemsetAsync(sums, 0, 256, stream);

    int ebl = (E + 255) / 256;
    int nbl = (N + 255) / 256;
    int nprobe = E < 4096 ? E : 4096;

    int eebl = ebl < EE_BLOCKS ? ebl : EE_BLOCKS;
    edge_enc<<<eebl, 256, 0, stream>>>(raw, ei, mask_raw, nprobe, ee_w1, ee_b1, ee_w2, ee_b2, ea, deg, sums, E);
    scan1<<<nbl, 256, 0, stream>>>(deg, part, N);
    scan23<<<nbl, 256, 0, stream>>>(deg, part, row_ofs, cursor, N, E, nbl);
    csr_fill<<<ebl, 256, 0, stream>>>(ei, cursor, mask_raw, nprobe, csr, E);
    pack_wh<<<129, 256, 0, stream>>>(wl_s, wr_s, wl_r, wr_r, bl_s, br_s, bl_r, br_r,
                                     we_s, we_r, att_s, att_r, bias_s, bias_r, sums, E,
                                     Wh, biasp, wpk, eflv, attvv, biasvv);
    node_gemm<<<(N + NG_BM - 1) / NG_BM, 256, 0, stream>>>(x, Wh, biasp, XLh, XR, N);
    gat_main<<<N, 128, 0, stream>>>(XLh, XR, ea, csr, row_ofs,
                                    wpk, eflv, attvv, biasvv,
                                    (float*)d_out, N);
}